// Round 11
// baseline (290.069 us; speedup 1.0000x reference)
//
#include <hip/hip_runtime.h>
#include <hip/hip_fp16.h>
#include <math.h>

// Problem constants (match reference)
#define NN 150000
#define NE 2400000
#define NG 1024
#define DIN 6
#define DH 32
#define DB 16
#define BN_EPS 1e-5f

#define FUSED_BLOCKS ((NN + 63) / 64)   // 2344 (all fused layers, 64 nodes/block)
#define RED_BLKS 64                     // stage-1 reduction blocks

// bucket sort params
#define NB 512            // buckets
#define NPB 293           // nodes per bucket (512*293 = 150016 >= NN); NPB < 512 so 9 bits
#define SCH 4096          // edges per scatter block
#define EPB 16            // edges per thread in scatter
#define CAP 8192          // fixed region per bucket (expected ~4690 edges)
#define NSCAT ((NE + SCH - 1) / SCH)  // 586

// inclusive Hillis-Steele scan of 512 ints in LDS with 256 threads
#define SCAN512(scarr, t)                                     \
    for (int off = 1; off < 512; off <<= 1) {                 \
        int v0 = (t >= off) ? scarr[t - off] : 0;             \
        int v1 = scarr[t + 256 - off];                        \
        __syncthreads();                                      \
        if (t >= off) scarr[t] += v0;                         \
        scarr[t + 256] += v1;                                 \
        __syncthreads();                                      \
    }

__device__ inline void addh8(float* a, uint4 v) {
    const __half2* hp = (const __half2*)&v;
#pragma unroll
    for (int i = 0; i < 4; ++i) {
        float2 f = __half22float2(hp[i]);
        a[2 * i] += f.x; a[2 * i + 1] += f.y;
    }
}

// ===== init: bucket cursors + graph bounds + x->fp16 table + stat counters =====
__global__ void init_cvt(const int* __restrict__ bat, const float* __restrict__ x,
                         int* __restrict__ bcur, int* __restrict__ gptr,
                         __half* __restrict__ x16, int* __restrict__ counters) {
    int i = blockIdx.x * blockDim.x + threadIdx.x;
    if (i < 3) counters[i] = 0;
    if (i < NB) bcur[i] = i * CAP;
    if (i <= NG) {
        int lo = 0, hi = NN;
        while (lo < hi) {
            int mid = (lo + hi) >> 1;
            if (bat[mid] < i) lo = mid + 1; else hi = mid;
        }
        gptr[i] = lo;
    }
    if (i < NN) {
        const float2* xs = (const float2*)(x + (long)i * DIN);
        float2 p0 = xs[0], p1 = xs[1], p2 = xs[2];
        uint4 v;
        unsigned* vp = (unsigned*)&v;
        __half2 h0 = __floats2half2_rn(p0.x, p0.y);
        __half2 h1 = __floats2half2_rn(p1.x, p1.y);
        __half2 h2 = __floats2half2_rn(p2.x, p2.y);
        __half2 h3 = __floats2half2_rn(0.f, 0.f);
        vp[0] = *(unsigned*)&h0; vp[1] = *(unsigned*)&h1;
        vp[2] = *(unsigned*)&h2; vp[3] = *(unsigned*)&h3;
        ((uint4*)x16)[i] = v;
    }
}

// block-local binning -> packed (src<<9|dst_local) writes into fixed bucket regions
__global__ void bucket_scatter(const int* __restrict__ ei, int* __restrict__ bcur,
                               unsigned* __restrict__ ebuf) {
    __shared__ int hist[NB];
    __shared__ int sc[NB];
    __shared__ int lcur[NB];
    __shared__ int gbase[NB];
    __shared__ unsigned stage[SCH];
    __shared__ unsigned short stageb[SCH];
    int t = threadIdx.x;
    long e0 = (long)blockIdx.x * SCH;
    int s16[EPB], d16[EPB];
    for (int i = t; i < NB; i += 256) hist[i] = 0;
    __syncthreads();
#pragma unroll
    for (int k = 0; k < EPB; ++k) {
        long idx = e0 + k * 256 + t;
        if (idx < NE) {
            s16[k] = ei[idx];
            d16[k] = ei[NE + idx];
            atomicAdd(&hist[d16[k] / NPB], 1);
        } else d16[k] = -1;
    }
    __syncthreads();
    for (int i = t; i < NB; i += 256) sc[i] = hist[i];
    __syncthreads();
    SCAN512(sc, t);
    for (int i = t; i < NB; i += 256) lcur[i] = sc[i] - hist[i];
    __syncthreads();
#pragma unroll
    for (int k = 0; k < EPB; ++k) {
        if (d16[k] >= 0) {
            int b = d16[k] / NPB;
            int p = atomicAdd(&lcur[b], 1);
            stage[p] = ((unsigned)s16[k] << 9) | (unsigned)(d16[k] - b * NPB);
            stageb[p] = (unsigned short)b;
        }
    }
    __syncthreads();
    for (int i = t; i < NB; i += 256) {
        int h = hist[i];
        gbase[i] = h ? atomicAdd(&bcur[i], h) : 0;
    }
    __syncthreads();
    int cnt = (int)((NE - e0) < SCH ? (NE - e0) : SCH);
    for (int i = t; i < cnt; i += 256) {
        int b = stageb[i];
        ebuf[gbase[b] + (i - (sc[b] - hist[b]))] = stage[i];
    }
}

// per-bucket LDS counting sort -> csr_src + DEGREE-SORTED slot permutation
// (rbeg/rend/nodeid indexed by slot; waves then get like-degree nodes)
__global__ void bucket_sort(const unsigned* __restrict__ ebuf, const int* __restrict__ bcur,
                            int* __restrict__ rbeg, int* __restrict__ rend,
                            int* __restrict__ nodeid, int* __restrict__ csr_src) {
    __shared__ int deg[NB];
    __shared__ int sc[NB];
    __shared__ int cur[NB];
    __shared__ int dh[NB];      // degree histogram -> exclusive base
    __shared__ int slotof[NB];  // local node j -> local slot
    __shared__ int srcbuf[CAP];
    int b = blockIdx.x, t = threadIdx.x;
    int node0 = b * NPB;
    int nlocal = (NN - node0) < NPB ? (NN - node0) : NPB;
    int ebase = b * CAP;
    int ecnt = bcur[b] - ebase;
    if (ecnt > CAP) ecnt = CAP;
    for (int i = t; i < NB; i += 256) { deg[i] = 0; dh[i] = 0; }
    __syncthreads();
    for (int i = t; i < ecnt; i += 256)
        atomicAdd(&deg[ebuf[ebase + i] & 511u], 1);
    __syncthreads();
    for (int i = t; i < NB; i += 256) sc[i] = deg[i];
    __syncthreads();
    SCAN512(sc, t);
    // degree histogram (clamped)
    for (int j = t; j < nlocal; j += 256) {
        int d = deg[j]; if (d > 511) d = 511;
        atomicAdd(&dh[d], 1);
    }
    __syncthreads();
    int c0 = dh[t], c1 = dh[t + 256];
    SCAN512(dh, t);
    int b0 = dh[t] - c0, b1 = dh[t + 256] - c1;
    __syncthreads();
    dh[t] = b0; dh[t + 256] = b1;
    __syncthreads();
    // deterministic stable slot assignment: thread d scans nodes in order
    for (int d = t; d < NB; d += 256) {
        int s0 = dh[d];
        for (int j = 0; j < nlocal; ++j) {
            int dj = deg[j]; if (dj > 511) dj = 511;
            if (dj == d) slotof[j] = s0++;
        }
    }
    __syncthreads();
    for (int j = t; j < nlocal; j += 256) {
        int st = sc[j] - deg[j];
        int slot = node0 + slotof[j];
        rbeg[slot] = ebase + st;
        rend[slot] = ebase + st + deg[j];
        nodeid[slot] = node0 + j;
        cur[j] = st;
    }
    __syncthreads();
    for (int i = t; i < ecnt; i += 256) {
        unsigned v = ebuf[ebase + i];
        int p = atomicAdd(&cur[v & 511u], 1);
        srcbuf[p] = (int)(v >> 9);
    }
    __syncthreads();
    for (int i = t; i < ecnt; i += 256) csr_src[ebase + i] = srcbuf[i];
}

// ======== fused layer 1: edge-split gather of x16 (L2-resident) + MLP + stats ========
__global__ void __launch_bounds__(256) fused_gin6(
    const int* __restrict__ rbeg, const int* __restrict__ rend,
    const int* __restrict__ nodeid,
    const int* __restrict__ csr_src, const __half* __restrict__ x16,
    const float* __restrict__ w1, const float* __restrict__ b1,
    const float* __restrict__ w2, const float* __restrict__ b2,
    __half* __restrict__ out, float* __restrict__ partial) {
    __shared__ float sw1[DIN * DH];
    __shared__ float sw2[DH * DH];
    __shared__ float sb1[DH];
    __shared__ float sb2[DH];
    __shared__ float bsum[DH];
    __shared__ float bsq[DH];
    int t = threadIdx.x;
    for (int i = t; i < DIN * DH; i += 256) sw1[i] = w1[i];
    for (int i = t; i < DH * DH; i += 256) sw2[i] = w2[i];
    if (t < DH) { sb1[t] = b1[t]; sb2[t] = b2[t]; bsum[t] = 0.f; bsq[t] = 0.f; }
    __syncthreads();

    int nl = t >> 2, sub = t & 3;
    int gslot = blockIdx.x * 64 + nl;
    bool valid = gslot < NN;
    int j0 = sub * 8;
    int qb = t & ~3;

    const uint4* xb = (const uint4*)x16;
    float a[8] = {0.f, 0.f, 0.f, 0.f, 0.f, 0.f, 0.f, 0.f};
    int node = 0, beg = 0, end = 0;
    if (valid) {
        node = nodeid[gslot];
        beg = rbeg[gslot]; end = rend[gslot];
        if (sub == 0) addh8(a, xb[node]);    // self term once
    }
    for (int e = beg + sub; e < end; e += 4) addh8(a, xb[csr_src[e]]);
#pragma unroll
    for (int i = 0; i < 8; ++i) {
        a[i] += __shfl_xor(a[i], 1);
        a[i] += __shfl_xor(a[i], 2);
    }

    float u[8];
#pragma unroll
    for (int i = 0; i < 8; ++i) {
        int j = j0 + i;
        float acc = sb1[j];
#pragma unroll
        for (int k = 0; k < DIN; ++k) acc += a[k] * sw1[k * DH + j];
        u[i] = fmaxf(acc, 0.f);
    }

    float r[8];
#pragma unroll
    for (int i = 0; i < 8; ++i) r[i] = sb2[j0 + i];
#pragma unroll
    for (int q = 0; q < 4; ++q) {
#pragma unroll
        for (int i = 0; i < 8; ++i) {
            float uk = __shfl(u[i], qb + q);
            int k = q * 8 + i;
            const float4* w4 = (const float4*)&sw2[k * DH + j0];
            float4 wa = w4[0], wb = w4[1];
            r[0] += uk * wa.x; r[1] += uk * wa.y; r[2] += uk * wa.z; r[3] += uk * wa.w;
            r[4] += uk * wb.x; r[5] += uk * wb.y; r[6] += uk * wb.z; r[7] += uk * wb.w;
        }
    }
#pragma unroll
    for (int i = 0; i < 8; ++i) r[i] = valid ? fmaxf(r[i], 0.f) : 0.f;

    if (valid) {
        uint4 o;
        unsigned* op = (unsigned*)&o;
#pragma unroll
        for (int i = 0; i < 4; ++i) {
            __half2 hh = __floats2half2_rn(r[2 * i], r[2 * i + 1]);
            op[i] = *(unsigned*)&hh;
        }
        ((uint4*)out)[(long)node * 4 + sub] = o;
    }

    float s[8], q[8];
#pragma unroll
    for (int i = 0; i < 8; ++i) { s[i] = r[i]; q[i] = r[i] * r[i]; }
#pragma unroll
    for (int o = 4; o < 64; o <<= 1) {
#pragma unroll
        for (int i = 0; i < 8; ++i) {
            s[i] += __shfl_xor(s[i], o);
            q[i] += __shfl_xor(q[i], o);
        }
    }
    if ((t & 63) < 4) {
#pragma unroll
        for (int i = 0; i < 8; ++i) {
            atomicAdd(&bsum[j0 + i], s[i]);
            atomicAdd(&bsq[j0 + i], q[i]);
        }
    }
    __syncthreads();
    if (t < 2 * DH) {
        float v = (t < DH) ? bsum[t] : bsq[t - DH];
        partial[(long)blockIdx.x * (2 * DH) + t] = v;
    }
}

// ======== fused layers 2/3 (fp16 h): gather + MLP via quad-shuffle ========
__global__ void __launch_bounds__(256) fused_gin16(
    const int* __restrict__ rbeg, const int* __restrict__ rend,
    const int* __restrict__ nodeid,
    const int* __restrict__ csr_src,
    const __half* __restrict__ h, const float* __restrict__ ss,
    const float* __restrict__ w1, const float* __restrict__ b1,
    const float* __restrict__ w2, const float* __restrict__ b2,
    __half* __restrict__ out, float* __restrict__ partial /* [gridDim][64] */) {
    __shared__ float sw1[DH * DH];
    __shared__ float sw2[DH * DH];
    __shared__ float sb1[DH];
    __shared__ float sb2[DH];
    __shared__ float bsum[DH];
    __shared__ float bsq[DH];
    int t = threadIdx.x;
    for (int i = t; i < DH * DH; i += 256) { sw1[i] = w1[i]; sw2[i] = w2[i]; }
    if (t < DH) { sb1[t] = b1[t]; sb2[t] = b2[t]; bsum[t] = 0.f; bsq[t] = 0.f; }
    __syncthreads();

    int nl = t >> 2, sub = t & 3;
    int gslot = blockIdx.x * 64 + nl;
    bool valid = gslot < NN;
    int j0 = sub * 8;
    int qb = t & ~3;      // quad base lane (same wave)

    const uint4* hb = (const uint4*)h;   // node row = 4 uint4
    float a[8] = {0.f, 0.f, 0.f, 0.f, 0.f, 0.f, 0.f, 0.f};
    int node = 0, beg = 0, end = 0;
    if (valid) {
        node = nodeid[gslot];
        beg = rbeg[gslot]; end = rend[gslot];
        addh8(a, hb[(long)node * 4 + sub]);     // self term
    }
    int e = beg;
    int nrem = end - beg;
    for (int i = 0; i < (nrem & ~3); i += 4) {
        int s0 = csr_src[e], s1 = csr_src[e + 1], s2 = csr_src[e + 2], s3 = csr_src[e + 3];
        e += 4;
        uint4 v0 = hb[(long)s0 * 4 + sub];
        uint4 v1 = hb[(long)s1 * 4 + sub];
        uint4 v2 = hb[(long)s2 * 4 + sub];
        uint4 v3 = hb[(long)s3 * 4 + sub];
        addh8(a, v0); addh8(a, v1); addh8(a, v2); addh8(a, v3);
    }
    for (; e < end; ++e) addh8(a, hb[(long)csr_src[e] * 4 + sub]);

    // ---- BN affine fold ----
    float cnt = (float)(end - beg + 1);
#pragma unroll
    for (int i = 0; i < 8; ++i)
        a[i] = a[i] * ss[j0 + i] + cnt * ss[DH + j0 + i];

    // ---- MLP layer A via quad-shuffle exchange ----
    float u[8];
#pragma unroll
    for (int i = 0; i < 8; ++i) u[i] = sb1[j0 + i];
#pragma unroll
    for (int q = 0; q < 4; ++q) {
#pragma unroll
        for (int i = 0; i < 8; ++i) {
            float ak = __shfl(a[i], qb + q);
            int k = q * 8 + i;
            const float4* w4 = (const float4*)&sw1[k * DH + j0];
            float4 wa = w4[0], wb = w4[1];
            u[0] += ak * wa.x; u[1] += ak * wa.y; u[2] += ak * wa.z; u[3] += ak * wa.w;
            u[4] += ak * wb.x; u[5] += ak * wb.y; u[6] += ak * wb.z; u[7] += ak * wb.w;
        }
    }
#pragma unroll
    for (int i = 0; i < 8; ++i) u[i] = fmaxf(u[i], 0.f);

    // ---- MLP layer B via quad-shuffle exchange ----
    float r[8];
#pragma unroll
    for (int i = 0; i < 8; ++i) r[i] = sb2[j0 + i];
#pragma unroll
    for (int q = 0; q < 4; ++q) {
#pragma unroll
        for (int i = 0; i < 8; ++i) {
            float uk = __shfl(u[i], qb + q);
            int k = q * 8 + i;
            const float4* w4 = (const float4*)&sw2[k * DH + j0];
            float4 wa = w4[0], wb = w4[1];
            r[0] += uk * wa.x; r[1] += uk * wa.y; r[2] += uk * wa.z; r[3] += uk * wa.w;
            r[4] += uk * wb.x; r[5] += uk * wb.y; r[6] += uk * wb.z; r[7] += uk * wb.w;
        }
    }
#pragma unroll
    for (int i = 0; i < 8; ++i) r[i] = valid ? fmaxf(r[i], 0.f) : 0.f;

    if (valid) {
        uint4 o;
        unsigned* op = (unsigned*)&o;
#pragma unroll
        for (int i = 0; i < 4; ++i) {
            __half2 hh = __floats2half2_rn(r[2 * i], r[2 * i + 1]);
            op[i] = *(unsigned*)&hh;
        }
        ((uint4*)out)[(long)node * 4 + sub] = o;
    }

    float s[8], q[8];
#pragma unroll
    for (int i = 0; i < 8; ++i) { s[i] = r[i]; q[i] = r[i] * r[i]; }
#pragma unroll
    for (int o = 4; o < 64; o <<= 1) {
#pragma unroll
        for (int i = 0; i < 8; ++i) {
            s[i] += __shfl_xor(s[i], o);
            q[i] += __shfl_xor(q[i], o);
        }
    }
    if ((t & 63) < 4) {
#pragma unroll
        for (int i = 0; i < 8; ++i) {
            atomicAdd(&bsum[j0 + i], s[i]);
            atomicAdd(&bsq[j0 + i], q[i]);
        }
    }
    __syncthreads();
    if (t < 2 * DH) {
        float v = (t < DH) ? bsum[t] : bsq[t - DH];
        partial[(long)blockIdx.x * (2 * DH) + t] = v;
    }
}

// ===== merged stats reduce: stage-1 fold + last-block finalize =====
__global__ void reduce_stats(const float* __restrict__ partial, int nblk,
                             float* __restrict__ partial2, int* __restrict__ counter,
                             const float* __restrict__ g, const float* __restrict__ be,
                             float* __restrict__ ss) {
    __shared__ float sred[4][64];
    __shared__ float sums[64];
    __shared__ int lastFlag;
    int t = threadIdx.x;           // 256
    int ch = t & 63, sub = t >> 6;
    int chunk = (nblk + RED_BLKS - 1) / RED_BLKS;
    int start = blockIdx.x * chunk;
    int end = start + chunk; if (end > nblk) end = nblk;
    float acc = 0.f;
    for (int r = start + sub; r < end; r += 4)
        acc += partial[(long)r * 64 + ch];
    sred[sub][ch] = acc;
    __syncthreads();
    if (t < 64)
        partial2[(long)blockIdx.x * 64 + t] =
            sred[0][t] + sred[1][t] + sred[2][t] + sred[3][t];
    __threadfence();               // release partial2 (device scope)
    __syncthreads();
    if (t == 0) lastFlag = (atomicAdd(counter, 1) == RED_BLKS - 1) ? 1 : 0;
    __syncthreads();
    if (!lastFlag) return;
    __threadfence();               // acquire side
    float acc2 = 0.f;
    for (int r = sub; r < RED_BLKS; r += 4) acc2 += partial2[(long)r * 64 + ch];
    sred[sub][ch] = acc2;
    __syncthreads();
    if (t < 64) sums[t] = sred[0][t] + sred[1][t] + sred[2][t] + sred[3][t];
    __syncthreads();
    if (t < DH) {
        float mu = sums[t] * (1.0f / NN);
        float var = sums[DH + t] * (1.0f / NN) - mu * mu;
        float sc = g[t] * rsqrtf(var + BN_EPS);
        ss[t] = sc;
        ss[DH + t] = be[t] - mu * sc;
    }
}

// ====== fused pool(BN affine folded) + head, one block per graph ======
__global__ void pool_head(const __half* __restrict__ h, const int* __restrict__ gptr,
                          const float* __restrict__ ss,
                          const float* __restrict__ wb, const float* __restrict__ bb,
                          const float* __restrict__ wm, const float* __restrict__ bm,
                          float* __restrict__ out) {
    __shared__ float swb[DH * DB];
    __shared__ float sbb[DB];
    __shared__ float swm[DB];
    __shared__ float semb[DH];
    int g = blockIdx.x;
    int t = threadIdx.x;           // 64 threads
    for (int i = t; i < DH * DB; i += 64) swb[i] = wb[i];
    if (t < DB) { sbb[t] = bb[t]; swm[t] = wm[t]; }
    int beg = gptr[g], end = gptr[g + 1];
    int sub = t & 3, nt = t >> 2;  // 16 node slots x 4 quarters
    const uint4* hb = (const uint4*)h;
    float acc[8] = {0.f, 0.f, 0.f, 0.f, 0.f, 0.f, 0.f, 0.f};
    for (int n = beg + nt; n < end; n += 16) addh8(acc, hb[(long)n * 4 + sub]);
#pragma unroll
    for (int o = 4; o < 64; o <<= 1) {
#pragma unroll
        for (int i = 0; i < 8; ++i) acc[i] += __shfl_xor(acc[i], o);
    }
    if (t < 4) {
        int c = end - beg;
        int j0 = t * 8;
        float inv = (c > 0) ? 1.0f / (float)c : 0.f;
#pragma unroll
        for (int i = 0; i < 8; ++i)
            semb[j0 + i] = (c > 0) ? ss[j0 + i] * (acc[i] * inv) + ss[DH + j0 + i] : 0.f;
    }
    __syncthreads();
    float z = 0.f;
    if (t < DB) {
        z = sbb[t];
#pragma unroll
        for (int k = 0; k < DH; ++k) z += semb[k] * swb[k * DB + t];
        z = fmaxf(z, 0.f) * swm[t];
    }
#pragma unroll
    for (int o = 1; o < DB; o <<= 1) z += __shfl_xor(z, o);
    if (t == 0) out[g] = 1.0f / (1.0f + expf(-(z + bm[0])));
}

extern "C" void kernel_launch(void* const* d_in, const int* in_sizes, int n_in,
                              void* d_out, int out_size, void* d_ws, size_t ws_size,
                              hipStream_t stream) {
    const float* x   = (const float*)d_in[0];
    const int*   ei  = (const int*)d_in[1];
    const int*   bat = (const int*)d_in[2];
    const float* w1a = (const float*)d_in[3];  const float* b1a = (const float*)d_in[4];
    const float* w1b = (const float*)d_in[5];  const float* b1b = (const float*)d_in[6];
    const float* g1  = (const float*)d_in[7];  const float* be1 = (const float*)d_in[8];
    const float* w2a = (const float*)d_in[9];  const float* b2a = (const float*)d_in[10];
    const float* w2b = (const float*)d_in[11]; const float* b2b = (const float*)d_in[12];
    const float* g2  = (const float*)d_in[13]; const float* be2 = (const float*)d_in[14];
    const float* w3a = (const float*)d_in[15]; const float* b3a = (const float*)d_in[16];
    const float* w3b = (const float*)d_in[17]; const float* b3b = (const float*)d_in[18];
    const float* g3  = (const float*)d_in[19]; const float* be3 = (const float*)d_in[20];
    const float* wb  = (const float*)d_in[21]; const float* bb  = (const float*)d_in[22];
    const float* wm  = (const float*)d_in[23]; const float* bm  = (const float*)d_in[24];
    float* out = (float*)d_out;

    // ---- workspace layout ----
    char* wsb = (char*)d_ws;
    __half* hbuf16 = (__half*)wsb;                              // NN*DH fp16 = 9.6 MB
    char* regB     = wsb + (size_t)NN * DH * 2;                 // NB*CAP*4 = 16.8 MB (ebuf, then abuf16)
    unsigned* ebuf = (unsigned*)regB;
    __half* abuf16 = (__half*)regB;
    int*   csr_src = (int*)(regB + (size_t)NB * CAP * 4);       // NB*CAP ints
    int*   rbeg    = csr_src + (long)NB * CAP;                  // NN
    int*   rend    = rbeg + NN;                                 // NN
    int*   nodeid  = rend + NN;                                 // NN
    int*   bcur    = nodeid + NN;                               // NB
    int*   gptr    = bcur + NB;                                 // NG+1
    int*   counters= gptr + NG + 1;                             // 3
    float* ss1     = (float*)(counters + 4);                    // 64
    float* ss2     = ss1 + 2 * DH;                              // 64
    float* ss3     = ss2 + 2 * DH;                              // 64
    float* partial2= ss3 + 2 * DH;                              // RED_BLKS*64
    float* partial = partial2 + (long)RED_BLKS * 64;            // FUSED_BLOCKS*64
    __half* x16    = (__half*)(partial + (long)FUSED_BLOCKS * 2 * DH); // NN*8 fp16 = 2.4 MB

    const int B = 256;
    int blkN = (NN + B - 1) / B;

    // ---- init (counters + bucket cursors + graph bounds + x16 table) ----
    init_cvt<<<blkN, B, 0, stream>>>(bat, x, bcur, gptr, x16, counters);

    // ---- CSR: block-local binning then per-bucket LDS counting sort + degree sort ----
    bucket_scatter<<<NSCAT, B, 0, stream>>>(ei, bcur, ebuf);
    bucket_sort<<<NB, B, 0, stream>>>(ebuf, bcur, rbeg, rend, nodeid, csr_src);

    // ---- layer 1 (fused, L2-resident x16 gathers): -> hbuf16 ----
    fused_gin6<<<FUSED_BLOCKS, B, 0, stream>>>(rbeg, rend, nodeid, csr_src, x16,
                                               w1a, b1a, w1b, b1b, hbuf16, partial);
    reduce_stats<<<RED_BLKS, B, 0, stream>>>(partial, FUSED_BLOCKS, partial2,
                                             counters + 0, g1, be1, ss1);

    // ---- layer 2 (fused): hbuf16 -> abuf16 (ebuf dead now) ----
    fused_gin16<<<FUSED_BLOCKS, B, 0, stream>>>(rbeg, rend, nodeid, csr_src, hbuf16, ss1,
                                                w2a, b2a, w2b, b2b, abuf16, partial);
    reduce_stats<<<RED_BLKS, B, 0, stream>>>(partial, FUSED_BLOCKS, partial2,
                                             counters + 1, g2, be2, ss2);

    // ---- layer 3 (fused): abuf16 -> hbuf16 ----
    fused_gin16<<<FUSED_BLOCKS, B, 0, stream>>>(rbeg, rend, nodeid, csr_src, abuf16, ss2,
                                                w3a, b3a, w3b, b3b, hbuf16, partial);
    reduce_stats<<<RED_BLKS, B, 0, stream>>>(partial, FUSED_BLOCKS, partial2,
                                             counters + 2, g3, be3, ss3);

    // ---- fused pool (BN3 inline) + head ----
    pool_head<<<NG, 64, 0, stream>>>(hbuf16, gptr, ss3, wb, bb, wm, bm, out);
}

// Round 12
// 248.633 us; speedup vs baseline: 1.1667x; 1.1667x over previous
//
#include <hip/hip_runtime.h>
#include <hip/hip_fp16.h>
#include <math.h>

// Problem constants (match reference)
#define NN 150000
#define NE 2400000
#define NG 1024
#define DIN 6
#define DH 32
#define DB 16
#define BN_EPS 1e-5f

#define FUSED_BLOCKS ((NN + 63) / 64)   // 2344 (all fused layers, 64 nodes/block)
#define RED_BLKS 64                     // stage-1 reduction blocks

// bucket sort params
#define NB 512            // buckets
#define NPB 293           // nodes per bucket (512*293 = 150016 >= NN); NPB < 512 so 9 bits
#define SCH 4096          // edges per scatter block
#define EPB 16            // edges per thread in scatter
#define CAP 8192          // fixed region per bucket (expected ~4690 edges)
#define NSCAT ((NE + SCH - 1) / SCH)  // 586

// inclusive Hillis-Steele scan of 512 ints in LDS with 256 threads
#define SCAN512(scarr, t)                                     \
    for (int off = 1; off < 512; off <<= 1) {                 \
        int v0 = (t >= off) ? scarr[t - off] : 0;             \
        int v1 = scarr[t + 256 - off];                        \
        __syncthreads();                                      \
        if (t >= off) scarr[t] += v0;                         \
        scarr[t + 256] += v1;                                 \
        __syncthreads();                                      \
    }

__device__ inline void addh8(float* a, uint4 v) {
    const __half2* hp = (const __half2*)&v;
#pragma unroll
    for (int i = 0; i < 4; ++i) {
        float2 f = __half22float2(hp[i]);
        a[2 * i] += f.x; a[2 * i + 1] += f.y;
    }
}

// ===== init: bucket cursors + graph bounds + x->fp16 table + stat counters =====
__global__ void init_cvt(const int* __restrict__ bat, const float* __restrict__ x,
                         int* __restrict__ bcur, int* __restrict__ gptr,
                         __half* __restrict__ x16, int* __restrict__ counters) {
    int i = blockIdx.x * blockDim.x + threadIdx.x;
    if (i < 3) counters[i] = 0;
    if (i < NB) bcur[i] = i * CAP;
    if (i <= NG) {
        int lo = 0, hi = NN;
        while (lo < hi) {
            int mid = (lo + hi) >> 1;
            if (bat[mid] < i) lo = mid + 1; else hi = mid;
        }
        gptr[i] = lo;
    }
    if (i < NN) {
        const float2* xs = (const float2*)(x + (long)i * DIN);
        float2 p0 = xs[0], p1 = xs[1], p2 = xs[2];
        uint4 v;
        unsigned* vp = (unsigned*)&v;
        __half2 h0 = __floats2half2_rn(p0.x, p0.y);
        __half2 h1 = __floats2half2_rn(p1.x, p1.y);
        __half2 h2 = __floats2half2_rn(p2.x, p2.y);
        __half2 h3 = __floats2half2_rn(0.f, 0.f);
        vp[0] = *(unsigned*)&h0; vp[1] = *(unsigned*)&h1;
        vp[2] = *(unsigned*)&h2; vp[3] = *(unsigned*)&h3;
        ((uint4*)x16)[i] = v;
    }
}

// block-local binning -> packed (src<<9|dst_local) writes into fixed bucket regions
__global__ void bucket_scatter(const int* __restrict__ ei, int* __restrict__ bcur,
                               unsigned* __restrict__ ebuf) {
    __shared__ int hist[NB];
    __shared__ int sc[NB];
    __shared__ int lcur[NB];
    __shared__ int gbase[NB];
    __shared__ unsigned stage[SCH];
    __shared__ unsigned short stageb[SCH];
    int t = threadIdx.x;
    long e0 = (long)blockIdx.x * SCH;
    int s16[EPB], d16[EPB];
    for (int i = t; i < NB; i += 256) hist[i] = 0;
    __syncthreads();
#pragma unroll
    for (int k = 0; k < EPB; ++k) {
        long idx = e0 + k * 256 + t;
        if (idx < NE) {
            s16[k] = ei[idx];
            d16[k] = ei[NE + idx];
            atomicAdd(&hist[d16[k] / NPB], 1);
        } else d16[k] = -1;
    }
    __syncthreads();
    for (int i = t; i < NB; i += 256) sc[i] = hist[i];
    __syncthreads();
    SCAN512(sc, t);
    for (int i = t; i < NB; i += 256) lcur[i] = sc[i] - hist[i];
    __syncthreads();
#pragma unroll
    for (int k = 0; k < EPB; ++k) {
        if (d16[k] >= 0) {
            int b = d16[k] / NPB;
            int p = atomicAdd(&lcur[b], 1);
            stage[p] = ((unsigned)s16[k] << 9) | (unsigned)(d16[k] - b * NPB);
            stageb[p] = (unsigned short)b;
        }
    }
    __syncthreads();
    for (int i = t; i < NB; i += 256) {
        int h = hist[i];
        gbase[i] = h ? atomicAdd(&bcur[i], h) : 0;
    }
    __syncthreads();
    int cnt = (int)((NE - e0) < SCH ? (NE - e0) : SCH);
    for (int i = t; i < cnt; i += 256) {
        int b = stageb[i];
        ebuf[gbase[b] + (i - (sc[b] - hist[b]))] = stage[i];
    }
}

// per-bucket LDS counting sort -> csr_src (fixed stride) + rbeg/rend per node
__global__ void bucket_sort(const unsigned* __restrict__ ebuf, const int* __restrict__ bcur,
                            int* __restrict__ rbeg, int* __restrict__ rend,
                            int* __restrict__ csr_src) {
    __shared__ int deg[NB];
    __shared__ int sc[NB];
    __shared__ int cur[NB];
    __shared__ int srcbuf[CAP];
    int b = blockIdx.x, t = threadIdx.x;
    int node0 = b * NPB;
    int nlocal = (NN - node0) < NPB ? (NN - node0) : NPB;
    int ebase = b * CAP;
    int ecnt = bcur[b] - ebase;
    if (ecnt > CAP) ecnt = CAP;
    for (int i = t; i < NB; i += 256) deg[i] = 0;
    __syncthreads();
    for (int i = t; i < ecnt; i += 256) {
        atomicAdd(&deg[ebuf[ebase + i] & 511u], 1);
    }
    __syncthreads();
    for (int i = t; i < NB; i += 256) sc[i] = deg[i];
    __syncthreads();
    SCAN512(sc, t);
    for (int j = t; j < nlocal; j += 256) {
        int st = sc[j] - deg[j];
        rbeg[node0 + j] = ebase + st;
        rend[node0 + j] = ebase + st + deg[j];
        cur[j] = st;
    }
    __syncthreads();
    for (int i = t; i < ecnt; i += 256) {
        unsigned v = ebuf[ebase + i];
        int p = atomicAdd(&cur[v & 511u], 1);
        srcbuf[p] = (int)(v >> 9);
    }
    __syncthreads();
    for (int i = t; i < ecnt; i += 256) csr_src[ebase + i] = srcbuf[i];
}

// ======== fused layer 1: edge-split gather of x16 (L2-resident) + MLP + stats ========
// 64 nodes / block, 4 threads / node (edge-split), quad-reduce agg.
__global__ void __launch_bounds__(256) fused_gin6(
    const int* __restrict__ rbeg, const int* __restrict__ rend,
    const int* __restrict__ csr_src, const __half* __restrict__ x16,
    const float* __restrict__ w1, const float* __restrict__ b1,
    const float* __restrict__ w2, const float* __restrict__ b2,
    __half* __restrict__ out, float* __restrict__ partial) {
    __shared__ float sw1[DIN * DH];
    __shared__ float sw2[DH * DH];
    __shared__ float sb1[DH];
    __shared__ float sb2[DH];
    __shared__ float bsum[DH];
    __shared__ float bsq[DH];
    int t = threadIdx.x;
    for (int i = t; i < DIN * DH; i += 256) sw1[i] = w1[i];
    for (int i = t; i < DH * DH; i += 256) sw2[i] = w2[i];
    if (t < DH) { sb1[t] = b1[t]; sb2[t] = b2[t]; bsum[t] = 0.f; bsq[t] = 0.f; }
    __syncthreads();

    int nl = t >> 2, sub = t & 3;
    int node = blockIdx.x * 64 + nl;
    bool valid = node < NN;
    int j0 = sub * 8;
    int qb = t & ~3;

    // ---- edge-split gather: thread sub takes edges beg+sub, beg+sub+4, ... ----
    const uint4* xb = (const uint4*)x16;
    float a[8] = {0.f, 0.f, 0.f, 0.f, 0.f, 0.f, 0.f, 0.f};
    int beg = 0, end = 0;
    if (valid) {
        beg = rbeg[node]; end = rend[node];
        if (sub == 0) addh8(a, xb[node]);    // self term once
    }
    for (int e = beg + sub; e < end; e += 4) addh8(a, xb[csr_src[e]]);
    // quad reduce -> every thread holds the full 6-ch (8 slot) agg
#pragma unroll
    for (int i = 0; i < 8; ++i) {
        a[i] += __shfl_xor(a[i], 1);
        a[i] += __shfl_xor(a[i], 2);
    }

    // ---- MLP layer A (IN=6, inputs local): thread computes its 8 outputs ----
    float u[8];
#pragma unroll
    for (int i = 0; i < 8; ++i) {
        int j = j0 + i;
        float acc = sb1[j];
#pragma unroll
        for (int k = 0; k < DIN; ++k) acc += a[k] * sw1[k * DH + j];
        u[i] = fmaxf(acc, 0.f);
    }

    // ---- MLP layer B via quad-shuffle exchange ----
    float r[8];
#pragma unroll
    for (int i = 0; i < 8; ++i) r[i] = sb2[j0 + i];
#pragma unroll
    for (int q = 0; q < 4; ++q) {
#pragma unroll
        for (int i = 0; i < 8; ++i) {
            float uk = __shfl(u[i], qb + q);
            int k = q * 8 + i;
            const float4* w4 = (const float4*)&sw2[k * DH + j0];
            float4 wa = w4[0], wb = w4[1];
            r[0] += uk * wa.x; r[1] += uk * wa.y; r[2] += uk * wa.z; r[3] += uk * wa.w;
            r[4] += uk * wb.x; r[5] += uk * wb.y; r[6] += uk * wb.z; r[7] += uk * wb.w;
        }
    }
#pragma unroll
    for (int i = 0; i < 8; ++i) r[i] = valid ? fmaxf(r[i], 0.f) : 0.f;

    if (valid) {
        uint4 o;
        unsigned* op = (unsigned*)&o;
#pragma unroll
        for (int i = 0; i < 4; ++i) {
            __half2 hh = __floats2half2_rn(r[2 * i], r[2 * i + 1]);
            op[i] = *(unsigned*)&hh;
        }
        ((uint4*)out)[(long)node * 4 + sub] = o;
    }

    // ---- stats ----
    float s[8], q[8];
#pragma unroll
    for (int i = 0; i < 8; ++i) { s[i] = r[i]; q[i] = r[i] * r[i]; }
#pragma unroll
    for (int o = 4; o < 64; o <<= 1) {
#pragma unroll
        for (int i = 0; i < 8; ++i) {
            s[i] += __shfl_xor(s[i], o);
            q[i] += __shfl_xor(q[i], o);
        }
    }
    if ((t & 63) < 4) {
#pragma unroll
        for (int i = 0; i < 8; ++i) {
            atomicAdd(&bsum[j0 + i], s[i]);
            atomicAdd(&bsq[j0 + i], q[i]);
        }
    }
    __syncthreads();
    if (t < 2 * DH) {
        float v = (t < DH) ? bsum[t] : bsq[t - DH];
        partial[(long)blockIdx.x * (2 * DH) + t] = v;
    }
}

// ======== fused layers 2/3 (fp16 h): gather + MLP via quad-shuffle ========
__global__ void __launch_bounds__(256) fused_gin16(
    const int* __restrict__ rbeg, const int* __restrict__ rend,
    const int* __restrict__ csr_src,
    const __half* __restrict__ h, const float* __restrict__ ss,
    const float* __restrict__ w1, const float* __restrict__ b1,
    const float* __restrict__ w2, const float* __restrict__ b2,
    __half* __restrict__ out, float* __restrict__ partial /* [gridDim][64] */) {
    __shared__ float sw1[DH * DH];
    __shared__ float sw2[DH * DH];
    __shared__ float sb1[DH];
    __shared__ float sb2[DH];
    __shared__ float bsum[DH];
    __shared__ float bsq[DH];
    int t = threadIdx.x;
    for (int i = t; i < DH * DH; i += 256) { sw1[i] = w1[i]; sw2[i] = w2[i]; }
    if (t < DH) { sb1[t] = b1[t]; sb2[t] = b2[t]; bsum[t] = 0.f; bsq[t] = 0.f; }
    __syncthreads();

    int nl = t >> 2, sub = t & 3;
    int node = blockIdx.x * 64 + nl;
    bool valid = node < NN;
    int j0 = sub * 8;
    int qb = t & ~3;      // quad base lane (same wave)

    // ---- gather (4 threads/node, 8 fp16 ch each = 16B loads), 4-deep unroll ----
    const uint4* hb = (const uint4*)h;   // node row = 4 uint4
    float a[8] = {0.f, 0.f, 0.f, 0.f, 0.f, 0.f, 0.f, 0.f};
    int beg = 0, end = 0;
    if (valid) {
        beg = rbeg[node]; end = rend[node];
        addh8(a, hb[(long)node * 4 + sub]);     // self term
    }
    int e = beg;
    int nrem = end - beg;
    for (int i = 0; i < (nrem & ~3); i += 4) {
        int s0 = csr_src[e], s1 = csr_src[e + 1], s2 = csr_src[e + 2], s3 = csr_src[e + 3];
        e += 4;
        uint4 v0 = hb[(long)s0 * 4 + sub];
        uint4 v1 = hb[(long)s1 * 4 + sub];
        uint4 v2 = hb[(long)s2 * 4 + sub];
        uint4 v3 = hb[(long)s3 * 4 + sub];
        addh8(a, v0); addh8(a, v1); addh8(a, v2); addh8(a, v3);
    }
    for (; e < end; ++e) addh8(a, hb[(long)csr_src[e] * 4 + sub]);

    // ---- BN affine fold (stays in registers) ----
    float cnt = (float)(end - beg + 1);
#pragma unroll
    for (int i = 0; i < 8; ++i)
        a[i] = a[i] * ss[j0 + i] + cnt * ss[DH + j0 + i];

    // ---- MLP layer A via quad-shuffle exchange ----
    float u[8];
#pragma unroll
    for (int i = 0; i < 8; ++i) u[i] = sb1[j0 + i];
#pragma unroll
    for (int q = 0; q < 4; ++q) {
#pragma unroll
        for (int i = 0; i < 8; ++i) {
            float ak = __shfl(a[i], qb + q);
            int k = q * 8 + i;
            const float4* w4 = (const float4*)&sw1[k * DH + j0];
            float4 wa = w4[0], wb = w4[1];
            u[0] += ak * wa.x; u[1] += ak * wa.y; u[2] += ak * wa.z; u[3] += ak * wa.w;
            u[4] += ak * wb.x; u[5] += ak * wb.y; u[6] += ak * wb.z; u[7] += ak * wb.w;
        }
    }
#pragma unroll
    for (int i = 0; i < 8; ++i) u[i] = fmaxf(u[i], 0.f);

    // ---- MLP layer B via quad-shuffle exchange ----
    float r[8];
#pragma unroll
    for (int i = 0; i < 8; ++i) r[i] = sb2[j0 + i];
#pragma unroll
    for (int q = 0; q < 4; ++q) {
#pragma unroll
        for (int i = 0; i < 8; ++i) {
            float uk = __shfl(u[i], qb + q);
            int k = q * 8 + i;
            const float4* w4 = (const float4*)&sw2[k * DH + j0];
            float4 wa = w4[0], wb = w4[1];
            r[0] += uk * wa.x; r[1] += uk * wa.y; r[2] += uk * wa.z; r[3] += uk * wa.w;
            r[4] += uk * wb.x; r[5] += uk * wb.y; r[6] += uk * wb.z; r[7] += uk * wb.w;
        }
    }
#pragma unroll
    for (int i = 0; i < 8; ++i) r[i] = valid ? fmaxf(r[i], 0.f) : 0.f;

    if (valid) {
        uint4 o;
        unsigned* op = (unsigned*)&o;
#pragma unroll
        for (int i = 0; i < 4; ++i) {
            __half2 hh = __floats2half2_rn(r[2 * i], r[2 * i + 1]);
            op[i] = *(unsigned*)&hh;
        }
        ((uint4*)out)[(long)node * 4 + sub] = o;
    }

    // ---- stats: butterfly over the 16 nodes in this wave, then LDS atomic ----
    float s[8], q[8];
#pragma unroll
    for (int i = 0; i < 8; ++i) { s[i] = r[i]; q[i] = r[i] * r[i]; }
#pragma unroll
    for (int o = 4; o < 64; o <<= 1) {
#pragma unroll
        for (int i = 0; i < 8; ++i) {
            s[i] += __shfl_xor(s[i], o);
            q[i] += __shfl_xor(q[i], o);
        }
    }
    if ((t & 63) < 4) {
#pragma unroll
        for (int i = 0; i < 8; ++i) {
            atomicAdd(&bsum[j0 + i], s[i]);
            atomicAdd(&bsq[j0 + i], q[i]);
        }
    }
    __syncthreads();
    if (t < 2 * DH) {
        float v = (t < DH) ? bsum[t] : bsq[t - DH];
        partial[(long)blockIdx.x * (2 * DH) + t] = v;
    }
}

// ===== merged stats reduce: stage-1 fold + last-block finalize =====
__global__ void reduce_stats(const float* __restrict__ partial, int nblk,
                             float* __restrict__ partial2, int* __restrict__ counter,
                             const float* __restrict__ g, const float* __restrict__ be,
                             float* __restrict__ ss) {
    __shared__ float sred[4][64];
    __shared__ float sums[64];
    __shared__ int lastFlag;
    int t = threadIdx.x;           // 256
    int ch = t & 63, sub = t >> 6;
    int chunk = (nblk + RED_BLKS - 1) / RED_BLKS;
    int start = blockIdx.x * chunk;
    int end = start + chunk; if (end > nblk) end = nblk;
    float acc = 0.f;
    for (int r = start + sub; r < end; r += 4)
        acc += partial[(long)r * 64 + ch];
    sred[sub][ch] = acc;
    __syncthreads();
    if (t < 64)
        partial2[(long)blockIdx.x * 64 + t] =
            sred[0][t] + sred[1][t] + sred[2][t] + sred[3][t];
    __threadfence();               // release partial2 (device scope)
    __syncthreads();
    if (t == 0) lastFlag = (atomicAdd(counter, 1) == RED_BLKS - 1) ? 1 : 0;
    __syncthreads();
    if (!lastFlag) return;
    __threadfence();               // acquire side
    float acc2 = 0.f;
    for (int r = sub; r < RED_BLKS; r += 4) acc2 += partial2[(long)r * 64 + ch];
    sred[sub][ch] = acc2;
    __syncthreads();
    if (t < 64) sums[t] = sred[0][t] + sred[1][t] + sred[2][t] + sred[3][t];
    __syncthreads();
    if (t < DH) {
        float mu = sums[t] * (1.0f / NN);
        float var = sums[DH + t] * (1.0f / NN) - mu * mu;
        float sc = g[t] * rsqrtf(var + BN_EPS);
        ss[t] = sc;
        ss[DH + t] = be[t] - mu * sc;
    }
}

// ====== fused pool(BN affine folded) + head, one block per graph ======
__global__ void pool_head(const __half* __restrict__ h, const int* __restrict__ gptr,
                          const float* __restrict__ ss,
                          const float* __restrict__ wb, const float* __restrict__ bb,
                          const float* __restrict__ wm, const float* __restrict__ bm,
                          float* __restrict__ out) {
    __shared__ float swb[DH * DB];
    __shared__ float sbb[DB];
    __shared__ float swm[DB];
    __shared__ float semb[DH];
    int g = blockIdx.x;
    int t = threadIdx.x;           // 64 threads
    for (int i = t; i < DH * DB; i += 64) swb[i] = wb[i];
    if (t < DB) { sbb[t] = bb[t]; swm[t] = wm[t]; }
    int beg = gptr[g], end = gptr[g + 1];
    int sub = t & 3, nt = t >> 2;  // 16 node slots x 4 quarters
    const uint4* hb = (const uint4*)h;
    float acc[8] = {0.f, 0.f, 0.f, 0.f, 0.f, 0.f, 0.f, 0.f};
    for (int n = beg + nt; n < end; n += 16) addh8(acc, hb[(long)n * 4 + sub]);
#pragma unroll
    for (int o = 4; o < 64; o <<= 1) {
#pragma unroll
        for (int i = 0; i < 8; ++i) acc[i] += __shfl_xor(acc[i], o);
    }
    if (t < 4) {
        int c = end - beg;
        int j0 = t * 8;
        float inv = (c > 0) ? 1.0f / (float)c : 0.f;
#pragma unroll
        for (int i = 0; i < 8; ++i)
            semb[j0 + i] = (c > 0) ? ss[j0 + i] * (acc[i] * inv) + ss[DH + j0 + i] : 0.f;
    }
    __syncthreads();
    float z = 0.f;
    if (t < DB) {
        z = sbb[t];
#pragma unroll
        for (int k = 0; k < DH; ++k) z += semb[k] * swb[k * DB + t];
        z = fmaxf(z, 0.f) * swm[t];
    }
#pragma unroll
    for (int o = 1; o < DB; o <<= 1) z += __shfl_xor(z, o);
    if (t == 0) out[g] = 1.0f / (1.0f + expf(-(z + bm[0])));
}

extern "C" void kernel_launch(void* const* d_in, const int* in_sizes, int n_in,
                              void* d_out, int out_size, void* d_ws, size_t ws_size,
                              hipStream_t stream) {
    const float* x   = (const float*)d_in[0];
    const int*   ei  = (const int*)d_in[1];
    const int*   bat = (const int*)d_in[2];
    const float* w1a = (const float*)d_in[3];  const float* b1a = (const float*)d_in[4];
    const float* w1b = (const float*)d_in[5];  const float* b1b = (const float*)d_in[6];
    const float* g1  = (const float*)d_in[7];  const float* be1 = (const float*)d_in[8];
    const float* w2a = (const float*)d_in[9];  const float* b2a = (const float*)d_in[10];
    const float* w2b = (const float*)d_in[11]; const float* b2b = (const float*)d_in[12];
    const float* g2  = (const float*)d_in[13]; const float* be2 = (const float*)d_in[14];
    const float* w3a = (const float*)d_in[15]; const float* b3a = (const float*)d_in[16];
    const float* w3b = (const float*)d_in[17]; const float* b3b = (const float*)d_in[18];
    const float* g3  = (const float*)d_in[19]; const float* be3 = (const float*)d_in[20];
    const float* wb  = (const float*)d_in[21]; const float* bb  = (const float*)d_in[22];
    const float* wm  = (const float*)d_in[23]; const float* bm  = (const float*)d_in[24];
    float* out = (float*)d_out;

    // ---- workspace layout ----
    char* wsb = (char*)d_ws;
    __half* hbuf16 = (__half*)wsb;                              // NN*DH fp16 = 9.6 MB
    char* regB     = wsb + (size_t)NN * DH * 2;                 // NB*CAP*4 = 16.8 MB (ebuf, then abuf16)
    unsigned* ebuf = (unsigned*)regB;
    __half* abuf16 = (__half*)regB;
    int*   csr_src = (int*)(regB + (size_t)NB * CAP * 4);       // NB*CAP ints
    int*   rbeg    = csr_src + (long)NB * CAP;                  // NN
    int*   rend    = rbeg + NN;                                 // NN
    int*   bcur    = rend + NN;                                 // NB
    int*   gptr    = bcur + NB;                                 // NG+1
    int*   counters= gptr + NG + 1;                             // 4 (3 used)
    float* ss1     = (float*)(counters + 4);                    // 64
    float* ss2     = ss1 + 2 * DH;                              // 64
    float* ss3     = ss2 + 2 * DH;                              // 64
    float* partial2= ss3 + 2 * DH;                              // RED_BLKS*64
    float* partial = partial2 + (long)RED_BLKS * 64;            // FUSED_BLOCKS*64
    __half* x16    = (__half*)(partial + (long)FUSED_BLOCKS * 2 * DH); // NN*8 fp16 = 2.4 MB

    const int B = 256;
    int blkN = (NN + B - 1) / B;

    // ---- init (counters + bucket cursors + graph bounds + x16 table) ----
    init_cvt<<<blkN, B, 0, stream>>>(bat, x, bcur, gptr, x16, counters);

    // ---- CSR: block-local binning then per-bucket LDS counting sort ----
    bucket_scatter<<<NSCAT, B, 0, stream>>>(ei, bcur, ebuf);
    bucket_sort<<<NB, B, 0, stream>>>(ebuf, bcur, rbeg, rend, csr_src);

    // ---- layer 1 (fused, L2-resident x16 gathers): -> hbuf16 ----
    fused_gin6<<<FUSED_BLOCKS, B, 0, stream>>>(rbeg, rend, csr_src, x16,
                                               w1a, b1a, w1b, b1b, hbuf16, partial);
    reduce_stats<<<RED_BLKS, B, 0, stream>>>(partial, FUSED_BLOCKS, partial2,
                                             counters + 0, g1, be1, ss1);

    // ---- layer 2 (fused): hbuf16 -> abuf16 (ebuf dead now) ----
    fused_gin16<<<FUSED_BLOCKS, B, 0, stream>>>(rbeg, rend, csr_src, hbuf16, ss1,
                                                w2a, b2a, w2b, b2b, abuf16, partial);
    reduce_stats<<<RED_BLKS, B, 0, stream>>>(partial, FUSED_BLOCKS, partial2,
                                             counters + 1, g2, be2, ss2);

    // ---- layer 3 (fused): abuf16 -> hbuf16 ----
    fused_gin16<<<FUSED_BLOCKS, B, 0, stream>>>(rbeg, rend, csr_src, abuf16, ss2,
                                                w3a, b3a, w3b, b3b, hbuf16, partial);
    reduce_stats<<<RED_BLKS, B, 0, stream>>>(partial, FUSED_BLOCKS, partial2,
                                             counters + 2, g3, be3, ss3);

    // ---- fused pool (BN3 inline) + head ----
    pool_head<<<NG, 64, 0, stream>>>(hbuf16, gptr, ss3, wb, bb, wm, bm, out);
}

// Round 13
// 232.003 us; speedup vs baseline: 1.2503x; 1.0717x over previous
//
#include <hip/hip_runtime.h>
#include <hip/hip_fp16.h>
#include <math.h>

// Problem constants (match reference)
#define NN 150000
#define NE 2400000
#define NG 1024
#define DIN 6
#define DH 32
#define DB 16
#define BN_EPS 1e-5f

#define FUSED_BLOCKS ((NN + 63) / 64)   // 2344 (all fused layers, 64 nodes/block)
#define RED_BLKS 64                     // stage-1 reduction blocks

// bucket sort params
#define NB 512            // buckets
#define NPB 293           // nodes per bucket (512*293 = 150016 >= NN); NPB < 512 so 9 bits
#define SCH 4096          // edges per scatter block
#define EPB 16            // edges per thread in scatter
#define CAP 8192          // fixed region per bucket (expected ~4690 edges)
#define NSCAT ((NE + SCH - 1) / SCH)  // 586

// inclusive Hillis-Steele scan of 512 ints in LDS with 256 threads
#define SCAN512(scarr, t)                                     \
    for (int off = 1; off < 512; off <<= 1) {                 \
        int v0 = (t >= off) ? scarr[t - off] : 0;             \
        int v1 = scarr[t + 256 - off];                        \
        __syncthreads();                                      \
        if (t >= off) scarr[t] += v0;                         \
        scarr[t + 256] += v1;                                 \
        __syncthreads();                                      \
    }

__device__ inline void addh8(float* a, uint4 v) {
    const __half2* hp = (const __half2*)&v;
#pragma unroll
    for (int i = 0; i < 4; ++i) {
        float2 f = __half22float2(hp[i]);
        a[2 * i] += f.x; a[2 * i + 1] += f.y;
    }
}

// ===== init: bucket cursors + graph bounds + x->fp16 table =====
__global__ void init_cvt(const int* __restrict__ bat, const float* __restrict__ x,
                         int* __restrict__ bcur, int* __restrict__ gptr,
                         __half* __restrict__ x16) {
    int i = blockIdx.x * blockDim.x + threadIdx.x;
    if (i < NB) bcur[i] = i * CAP;
    if (i <= NG) {
        int lo = 0, hi = NN;
        while (lo < hi) {
            int mid = (lo + hi) >> 1;
            if (bat[mid] < i) lo = mid + 1; else hi = mid;
        }
        gptr[i] = lo;
    }
    if (i < NN) {
        const float2* xs = (const float2*)(x + (long)i * DIN);
        float2 p0 = xs[0], p1 = xs[1], p2 = xs[2];
        uint4 v;
        unsigned* vp = (unsigned*)&v;
        __half2 h0 = __floats2half2_rn(p0.x, p0.y);
        __half2 h1 = __floats2half2_rn(p1.x, p1.y);
        __half2 h2 = __floats2half2_rn(p2.x, p2.y);
        __half2 h3 = __floats2half2_rn(0.f, 0.f);
        vp[0] = *(unsigned*)&h0; vp[1] = *(unsigned*)&h1;
        vp[2] = *(unsigned*)&h2; vp[3] = *(unsigned*)&h3;
        ((uint4*)x16)[i] = v;
    }
}

// block-local binning -> packed (src<<9|dst_local) writes into fixed bucket regions
__global__ void bucket_scatter(const int* __restrict__ ei, int* __restrict__ bcur,
                               unsigned* __restrict__ ebuf) {
    __shared__ int hist[NB];
    __shared__ int sc[NB];
    __shared__ int lcur[NB];
    __shared__ int gbase[NB];
    __shared__ unsigned stage[SCH];
    __shared__ unsigned short stageb[SCH];
    int t = threadIdx.x;
    long e0 = (long)blockIdx.x * SCH;
    int s16[EPB], d16[EPB];
    for (int i = t; i < NB; i += 256) hist[i] = 0;
    __syncthreads();
#pragma unroll
    for (int k = 0; k < EPB; ++k) {
        long idx = e0 + k * 256 + t;
        if (idx < NE) {
            s16[k] = ei[idx];
            d16[k] = ei[NE + idx];
            atomicAdd(&hist[d16[k] / NPB], 1);
        } else d16[k] = -1;
    }
    __syncthreads();
    for (int i = t; i < NB; i += 256) sc[i] = hist[i];
    __syncthreads();
    SCAN512(sc, t);
    for (int i = t; i < NB; i += 256) lcur[i] = sc[i] - hist[i];
    __syncthreads();
#pragma unroll
    for (int k = 0; k < EPB; ++k) {
        if (d16[k] >= 0) {
            int b = d16[k] / NPB;
            int p = atomicAdd(&lcur[b], 1);
            stage[p] = ((unsigned)s16[k] << 9) | (unsigned)(d16[k] - b * NPB);
            stageb[p] = (unsigned short)b;
        }
    }
    __syncthreads();
    for (int i = t; i < NB; i += 256) {
        int h = hist[i];
        gbase[i] = h ? atomicAdd(&bcur[i], h) : 0;
    }
    __syncthreads();
    int cnt = (int)((NE - e0) < SCH ? (NE - e0) : SCH);
    for (int i = t; i < cnt; i += 256) {
        int b = stageb[i];
        ebuf[gbase[b] + (i - (sc[b] - hist[b]))] = stage[i];
    }
}

// per-bucket LDS counting sort -> csr_src (fixed stride) + rbeg/rend per node
__global__ void bucket_sort(const unsigned* __restrict__ ebuf, const int* __restrict__ bcur,
                            int* __restrict__ rbeg, int* __restrict__ rend,
                            int* __restrict__ csr_src) {
    __shared__ int deg[NB];
    __shared__ int sc[NB];
    __shared__ int cur[NB];
    __shared__ int srcbuf[CAP];
    int b = blockIdx.x, t = threadIdx.x;
    int node0 = b * NPB;
    int nlocal = (NN - node0) < NPB ? (NN - node0) : NPB;
    int ebase = b * CAP;
    int ecnt = bcur[b] - ebase;
    if (ecnt > CAP) ecnt = CAP;
    for (int i = t; i < NB; i += 256) deg[i] = 0;
    __syncthreads();
    for (int i = t; i < ecnt; i += 256) {
        atomicAdd(&deg[ebuf[ebase + i] & 511u], 1);
    }
    __syncthreads();
    for (int i = t; i < NB; i += 256) sc[i] = deg[i];
    __syncthreads();
    SCAN512(sc, t);
    for (int j = t; j < nlocal; j += 256) {
        int st = sc[j] - deg[j];
        rbeg[node0 + j] = ebase + st;
        rend[node0 + j] = ebase + st + deg[j];
        cur[j] = st;
    }
    __syncthreads();
    for (int i = t; i < ecnt; i += 256) {
        unsigned v = ebuf[ebase + i];
        int p = atomicAdd(&cur[v & 511u], 1);
        srcbuf[p] = (int)(v >> 9);
    }
    __syncthreads();
    for (int i = t; i < ecnt; i += 256) csr_src[ebase + i] = srcbuf[i];
}

// ======== fused layer 1: edge-split gather of x16 (L2-resident) + MLP + stats ========
// 64 nodes / block, 4 threads / node (edge-split), quad-reduce agg.
__global__ void __launch_bounds__(256) fused_gin6(
    const int* __restrict__ rbeg, const int* __restrict__ rend,
    const int* __restrict__ csr_src, const __half* __restrict__ x16,
    const float* __restrict__ w1, const float* __restrict__ b1,
    const float* __restrict__ w2, const float* __restrict__ b2,
    __half* __restrict__ out, float* __restrict__ partial) {
    __shared__ float sw1[DIN * DH];
    __shared__ float sw2[DH * DH];
    __shared__ float sb1[DH];
    __shared__ float sb2[DH];
    __shared__ float bsum[DH];
    __shared__ float bsq[DH];
    int t = threadIdx.x;
    for (int i = t; i < DIN * DH; i += 256) sw1[i] = w1[i];
    for (int i = t; i < DH * DH; i += 256) sw2[i] = w2[i];
    if (t < DH) { sb1[t] = b1[t]; sb2[t] = b2[t]; bsum[t] = 0.f; bsq[t] = 0.f; }
    __syncthreads();

    int nl = t >> 2, sub = t & 3;
    int node = blockIdx.x * 64 + nl;
    bool valid = node < NN;
    int j0 = sub * 8;
    int qb = t & ~3;

    // ---- edge-split gather: thread sub takes edges beg+sub, beg+sub+4, ... ----
    const uint4* xb = (const uint4*)x16;
    float a[8] = {0.f, 0.f, 0.f, 0.f, 0.f, 0.f, 0.f, 0.f};
    int beg = 0, end = 0;
    if (valid) {
        beg = rbeg[node]; end = rend[node];
        if (sub == 0) addh8(a, xb[node]);    // self term once
    }
    for (int e = beg + sub; e < end; e += 4) addh8(a, xb[csr_src[e]]);
    // quad reduce -> every thread holds the full 6-ch (8 slot) agg
#pragma unroll
    for (int i = 0; i < 8; ++i) {
        a[i] += __shfl_xor(a[i], 1);
        a[i] += __shfl_xor(a[i], 2);
    }

    // ---- MLP layer A (IN=6, inputs local): thread computes its 8 outputs ----
    float u[8];
#pragma unroll
    for (int i = 0; i < 8; ++i) {
        int j = j0 + i;
        float acc = sb1[j];
#pragma unroll
        for (int k = 0; k < DIN; ++k) acc += a[k] * sw1[k * DH + j];
        u[i] = fmaxf(acc, 0.f);
    }

    // ---- MLP layer B via quad-shuffle exchange ----
    float r[8];
#pragma unroll
    for (int i = 0; i < 8; ++i) r[i] = sb2[j0 + i];
#pragma unroll
    for (int q = 0; q < 4; ++q) {
#pragma unroll
        for (int i = 0; i < 8; ++i) {
            float uk = __shfl(u[i], qb + q);
            int k = q * 8 + i;
            const float4* w4 = (const float4*)&sw2[k * DH + j0];
            float4 wa = w4[0], wb = w4[1];
            r[0] += uk * wa.x; r[1] += uk * wa.y; r[2] += uk * wa.z; r[3] += uk * wa.w;
            r[4] += uk * wb.x; r[5] += uk * wb.y; r[6] += uk * wb.z; r[7] += uk * wb.w;
        }
    }
#pragma unroll
    for (int i = 0; i < 8; ++i) r[i] = valid ? fmaxf(r[i], 0.f) : 0.f;

    if (valid) {
        uint4 o;
        unsigned* op = (unsigned*)&o;
#pragma unroll
        for (int i = 0; i < 4; ++i) {
            __half2 hh = __floats2half2_rn(r[2 * i], r[2 * i + 1]);
            op[i] = *(unsigned*)&hh;
        }
        ((uint4*)out)[(long)node * 4 + sub] = o;
    }

    // ---- stats ----
    float s[8], q[8];
#pragma unroll
    for (int i = 0; i < 8; ++i) { s[i] = r[i]; q[i] = r[i] * r[i]; }
#pragma unroll
    for (int o = 4; o < 64; o <<= 1) {
#pragma unroll
        for (int i = 0; i < 8; ++i) {
            s[i] += __shfl_xor(s[i], o);
            q[i] += __shfl_xor(q[i], o);
        }
    }
    if ((t & 63) < 4) {
#pragma unroll
        for (int i = 0; i < 8; ++i) {
            atomicAdd(&bsum[j0 + i], s[i]);
            atomicAdd(&bsq[j0 + i], q[i]);
        }
    }
    __syncthreads();
    if (t < 2 * DH) {
        float v = (t < DH) ? bsum[t] : bsq[t - DH];
        partial[(long)blockIdx.x * (2 * DH) + t] = v;
    }
}

// ======== fused layers 2/3 (fp16 h): gather + MLP via quad-shuffle; 8-deep burst ========
__global__ void __launch_bounds__(256) fused_gin16(
    const int* __restrict__ rbeg, const int* __restrict__ rend,
    const int* __restrict__ csr_src,
    const __half* __restrict__ h, const float* __restrict__ ss,
    const float* __restrict__ w1, const float* __restrict__ b1,
    const float* __restrict__ w2, const float* __restrict__ b2,
    __half* __restrict__ out, float* __restrict__ partial /* [gridDim][64] */) {
    __shared__ float sw1[DH * DH];
    __shared__ float sw2[DH * DH];
    __shared__ float sb1[DH];
    __shared__ float sb2[DH];
    __shared__ float bsum[DH];
    __shared__ float bsq[DH];
    int t = threadIdx.x;
    for (int i = t; i < DH * DH; i += 256) { sw1[i] = w1[i]; sw2[i] = w2[i]; }
    if (t < DH) { sb1[t] = b1[t]; sb2[t] = b2[t]; bsum[t] = 0.f; bsq[t] = 0.f; }
    __syncthreads();

    int nl = t >> 2, sub = t & 3;
    int node = blockIdx.x * 64 + nl;
    bool valid = node < NN;
    int j0 = sub * 8;
    int qb = t & ~3;      // quad base lane (same wave)

    // ---- gather (4 threads/node, 8 fp16 ch each = 16B loads), 8-deep burst ----
    const uint4* hb = (const uint4*)h;   // node row = 4 uint4
    float a[8] = {0.f, 0.f, 0.f, 0.f, 0.f, 0.f, 0.f, 0.f};
    int beg = 0, end = 0;
    if (valid) {
        beg = rbeg[node]; end = rend[node];
        addh8(a, hb[(long)node * 4 + sub]);     // self term
    }
    int e = beg;
    int nrem = end - beg;
    for (int i = 0; i < (nrem & ~7); i += 8) {
        int s0 = csr_src[e], s1 = csr_src[e + 1], s2 = csr_src[e + 2], s3 = csr_src[e + 3];
        int s4 = csr_src[e + 4], s5 = csr_src[e + 5], s6 = csr_src[e + 6], s7 = csr_src[e + 7];
        e += 8;
        uint4 v0 = hb[(long)s0 * 4 + sub];
        uint4 v1 = hb[(long)s1 * 4 + sub];
        uint4 v2 = hb[(long)s2 * 4 + sub];
        uint4 v3 = hb[(long)s3 * 4 + sub];
        uint4 v4 = hb[(long)s4 * 4 + sub];
        uint4 v5 = hb[(long)s5 * 4 + sub];
        uint4 v6 = hb[(long)s6 * 4 + sub];
        uint4 v7 = hb[(long)s7 * 4 + sub];
        addh8(a, v0); addh8(a, v1); addh8(a, v2); addh8(a, v3);
        addh8(a, v4); addh8(a, v5); addh8(a, v6); addh8(a, v7);
    }
    if (nrem & 4) {
        int s0 = csr_src[e], s1 = csr_src[e + 1], s2 = csr_src[e + 2], s3 = csr_src[e + 3];
        e += 4;
        uint4 v0 = hb[(long)s0 * 4 + sub];
        uint4 v1 = hb[(long)s1 * 4 + sub];
        uint4 v2 = hb[(long)s2 * 4 + sub];
        uint4 v3 = hb[(long)s3 * 4 + sub];
        addh8(a, v0); addh8(a, v1); addh8(a, v2); addh8(a, v3);
    }
    for (; e < end; ++e) addh8(a, hb[(long)csr_src[e] * 4 + sub]);

    // ---- BN affine fold (stays in registers) ----
    float cnt = (float)(end - beg + 1);
#pragma unroll
    for (int i = 0; i < 8; ++i)
        a[i] = a[i] * ss[j0 + i] + cnt * ss[DH + j0 + i];

    // ---- MLP layer A via quad-shuffle exchange ----
    float u[8];
#pragma unroll
    for (int i = 0; i < 8; ++i) u[i] = sb1[j0 + i];
#pragma unroll
    for (int q = 0; q < 4; ++q) {
#pragma unroll
        for (int i = 0; i < 8; ++i) {
            float ak = __shfl(a[i], qb + q);
            int k = q * 8 + i;
            const float4* w4 = (const float4*)&sw1[k * DH + j0];
            float4 wa = w4[0], wb = w4[1];
            u[0] += ak * wa.x; u[1] += ak * wa.y; u[2] += ak * wa.z; u[3] += ak * wa.w;
            u[4] += ak * wb.x; u[5] += ak * wb.y; u[6] += ak * wb.z; u[7] += ak * wb.w;
        }
    }
#pragma unroll
    for (int i = 0; i < 8; ++i) u[i] = fmaxf(u[i], 0.f);

    // ---- MLP layer B via quad-shuffle exchange ----
    float r[8];
#pragma unroll
    for (int i = 0; i < 8; ++i) r[i] = sb2[j0 + i];
#pragma unroll
    for (int q = 0; q < 4; ++q) {
#pragma unroll
        for (int i = 0; i < 8; ++i) {
            float uk = __shfl(u[i], qb + q);
            int k = q * 8 + i;
            const float4* w4 = (const float4*)&sw2[k * DH + j0];
            float4 wa = w4[0], wb = w4[1];
            r[0] += uk * wa.x; r[1] += uk * wa.y; r[2] += uk * wa.z; r[3] += uk * wa.w;
            r[4] += uk * wb.x; r[5] += uk * wb.y; r[6] += uk * wb.z; r[7] += uk * wb.w;
        }
    }
#pragma unroll
    for (int i = 0; i < 8; ++i) r[i] = valid ? fmaxf(r[i], 0.f) : 0.f;

    if (valid) {
        uint4 o;
        unsigned* op = (unsigned*)&o;
#pragma unroll
        for (int i = 0; i < 4; ++i) {
            __half2 hh = __floats2half2_rn(r[2 * i], r[2 * i + 1]);
            op[i] = *(unsigned*)&hh;
        }
        ((uint4*)out)[(long)node * 4 + sub] = o;
    }

    // ---- stats: butterfly over the 16 nodes in this wave, then LDS atomic ----
    float s[8], q[8];
#pragma unroll
    for (int i = 0; i < 8; ++i) { s[i] = r[i]; q[i] = r[i] * r[i]; }
#pragma unroll
    for (int o = 4; o < 64; o <<= 1) {
#pragma unroll
        for (int i = 0; i < 8; ++i) {
            s[i] += __shfl_xor(s[i], o);
            q[i] += __shfl_xor(q[i], o);
        }
    }
    if ((t & 63) < 4) {
#pragma unroll
        for (int i = 0; i < 8; ++i) {
            atomicAdd(&bsum[j0 + i], s[i]);
            atomicAdd(&bsq[j0 + i], q[i]);
        }
    }
    __syncthreads();
    if (t < 2 * DH) {
        float v = (t < DH) ? bsum[t] : bsq[t - DH];
        partial[(long)blockIdx.x * (2 * DH) + t] = v;
    }
}

// ===== stage 1: fold partial[nblk][64] -> partial2[RED_BLKS][64], coalesced =====
__global__ void reduce_partial(const float* __restrict__ partial, int nblk,
                               float* __restrict__ partial2) {
    __shared__ float sred[4][64];
    int t = threadIdx.x;           // 256
    int ch = t & 63, sub = t >> 6;
    int chunk = (nblk + RED_BLKS - 1) / RED_BLKS;
    int start = blockIdx.x * chunk;
    int end = start + chunk; if (end > nblk) end = nblk;
    float acc = 0.f;
    for (int r = start + sub; r < end; r += 4)
        acc += partial[(long)r * 64 + ch];
    sred[sub][ch] = acc;
    __syncthreads();
    if (t < 64)
        partial2[(long)blockIdx.x * 64 + t] =
            sred[0][t] + sred[1][t] + sred[2][t] + sred[3][t];
}

// ===== stage 2: fold partial2 + finalize BN scale/shift =====
__global__ void finalize_stats(const float* __restrict__ partial2,
                               const float* __restrict__ g, const float* __restrict__ be,
                               float* __restrict__ ss) {
    __shared__ float sred[4][64];
    __shared__ float sums[64];
    int t = threadIdx.x;           // 256
    int ch = t & 63, sub = t >> 6;
    float acc = 0.f;
    for (int r = sub; r < RED_BLKS; r += 4) acc += partial2[(long)r * 64 + ch];
    sred[sub][ch] = acc;
    __syncthreads();
    if (t < 64) sums[t] = sred[0][t] + sred[1][t] + sred[2][t] + sred[3][t];
    __syncthreads();
    if (t < DH) {
        float mu = sums[t] * (1.0f / NN);
        float var = sums[DH + t] * (1.0f / NN) - mu * mu;
        float sc = g[t] * rsqrtf(var + BN_EPS);
        ss[t] = sc;
        ss[DH + t] = be[t] - mu * sc;
    }
}

// ====== fused pool(BN affine folded) + head, one block per graph ======
__global__ void pool_head(const __half* __restrict__ h, const int* __restrict__ gptr,
                          const float* __restrict__ ss,
                          const float* __restrict__ wb, const float* __restrict__ bb,
                          const float* __restrict__ wm, const float* __restrict__ bm,
                          float* __restrict__ out) {
    __shared__ float swb[DH * DB];
    __shared__ float sbb[DB];
    __shared__ float swm[DB];
    __shared__ float semb[DH];
    int g = blockIdx.x;
    int t = threadIdx.x;           // 64 threads
    for (int i = t; i < DH * DB; i += 64) swb[i] = wb[i];
    if (t < DB) { sbb[t] = bb[t]; swm[t] = wm[t]; }
    int beg = gptr[g], end = gptr[g + 1];
    int sub = t & 3, nt = t >> 2;  // 16 node slots x 4 quarters
    const uint4* hb = (const uint4*)h;
    float acc[8] = {0.f, 0.f, 0.f, 0.f, 0.f, 0.f, 0.f, 0.f};
    for (int n = beg + nt; n < end; n += 16) addh8(acc, hb[(long)n * 4 + sub]);
#pragma unroll
    for (int o = 4; o < 64; o <<= 1) {
#pragma unroll
        for (int i = 0; i < 8; ++i) acc[i] += __shfl_xor(acc[i], o);
    }
    if (t < 4) {
        int c = end - beg;
        int j0 = t * 8;
        float inv = (c > 0) ? 1.0f / (float)c : 0.f;
#pragma unroll
        for (int i = 0; i < 8; ++i)
            semb[j0 + i] = (c > 0) ? ss[j0 + i] * (acc[i] * inv) + ss[DH + j0 + i] : 0.f;
    }
    __syncthreads();
    float z = 0.f;
    if (t < DB) {
        z = sbb[t];
#pragma unroll
        for (int k = 0; k < DH; ++k) z += semb[k] * swb[k * DB + t];
        z = fmaxf(z, 0.f) * swm[t];
    }
#pragma unroll
    for (int o = 1; o < DB; o <<= 1) z += __shfl_xor(z, o);
    if (t == 0) out[g] = 1.0f / (1.0f + expf(-(z + bm[0])));
}

extern "C" void kernel_launch(void* const* d_in, const int* in_sizes, int n_in,
                              void* d_out, int out_size, void* d_ws, size_t ws_size,
                              hipStream_t stream) {
    const float* x   = (const float*)d_in[0];
    const int*   ei  = (const int*)d_in[1];
    const int*   bat = (const int*)d_in[2];
    const float* w1a = (const float*)d_in[3];  const float* b1a = (const float*)d_in[4];
    const float* w1b = (const float*)d_in[5];  const float* b1b = (const float*)d_in[6];
    const float* g1  = (const float*)d_in[7];  const float* be1 = (const float*)d_in[8];
    const float* w2a = (const float*)d_in[9];  const float* b2a = (const float*)d_in[10];
    const float* w2b = (const float*)d_in[11]; const float* b2b = (const float*)d_in[12];
    const float* g2  = (const float*)d_in[13]; const float* be2 = (const float*)d_in[14];
    const float* w3a = (const float*)d_in[15]; const float* b3a = (const float*)d_in[16];
    const float* w3b = (const float*)d_in[17]; const float* b3b = (const float*)d_in[18];
    const float* g3  = (const float*)d_in[19]; const float* be3 = (const float*)d_in[20];
    const float* wb  = (const float*)d_in[21]; const float* bb  = (const float*)d_in[22];
    const float* wm  = (const float*)d_in[23]; const float* bm  = (const float*)d_in[24];
    float* out = (float*)d_out;

    // ---- workspace layout ----
    char* wsb = (char*)d_ws;
    __half* hbuf16 = (__half*)wsb;                              // NN*DH fp16 = 9.6 MB
    char* regB     = wsb + (size_t)NN * DH * 2;                 // NB*CAP*4 = 16.8 MB (ebuf, then abuf16)
    unsigned* ebuf = (unsigned*)regB;
    __half* abuf16 = (__half*)regB;
    int*   csr_src = (int*)(regB + (size_t)NB * CAP * 4);       // NB*CAP ints
    int*   rbeg    = csr_src + (long)NB * CAP;                  // NN
    int*   rend    = rbeg + NN;                                 // NN
    int*   bcur    = rend + NN;                                 // NB
    int*   gptr    = bcur + NB;                                 // NG+1
    float* ss1     = (float*)(gptr + NG + 1);                   // 64
    float* ss2     = ss1 + 2 * DH;                              // 64
    float* ss3     = ss2 + 2 * DH;                              // 64
    float* partial2= ss3 + 2 * DH;                              // RED_BLKS*64
    float* partial = partial2 + (long)RED_BLKS * 64;            // FUSED_BLOCKS*64
    __half* x16    = (__half*)(partial + (long)FUSED_BLOCKS * 2 * DH); // NN*8 fp16 = 2.4 MB

    const int B = 256;
    int blkN = (NN + B - 1) / B;

    // ---- init (bucket cursors + graph bounds + x16 table) ----
    init_cvt<<<blkN, B, 0, stream>>>(bat, x, bcur, gptr, x16);

    // ---- CSR: block-local binning then per-bucket LDS counting sort ----
    bucket_scatter<<<NSCAT, B, 0, stream>>>(ei, bcur, ebuf);
    bucket_sort<<<NB, B, 0, stream>>>(ebuf, bcur, rbeg, rend, csr_src);

    // ---- layer 1 (fused, L2-resident x16 gathers): -> hbuf16 ----
    fused_gin6<<<FUSED_BLOCKS, B, 0, stream>>>(rbeg, rend, csr_src, x16,
                                               w1a, b1a, w1b, b1b, hbuf16, partial);
    reduce_partial<<<RED_BLKS, B, 0, stream>>>(partial, FUSED_BLOCKS, partial2);
    finalize_stats<<<1, B, 0, stream>>>(partial2, g1, be1, ss1);

    // ---- layer 2 (fused): hbuf16 -> abuf16 (ebuf dead now) ----
    fused_gin16<<<FUSED_BLOCKS, B, 0, stream>>>(rbeg, rend, csr_src, hbuf16, ss1,
                                                w2a, b2a, w2b, b2b, abuf16, partial);
    reduce_partial<<<RED_BLKS, B, 0, stream>>>(partial, FUSED_BLOCKS, partial2);
    finalize_stats<<<1, B, 0, stream>>>(partial2, g2, be2, ss2);

    // ---- layer 3 (fused): abuf16 -> hbuf16 ----
    fused_gin16<<<FUSED_BLOCKS, B, 0, stream>>>(rbeg, rend, csr_src, abuf16, ss2,
                                                w3a, b3a, w3b, b3b, hbuf16, partial);
    reduce_partial<<<RED_BLKS, B, 0, stream>>>(partial, FUSED_BLOCKS, partial2);
    finalize_stats<<<1, B, 0, stream>>>(partial2, g3, be3, ss3);

    // ---- fused pool (BN3 inline) + head ----
    pool_head<<<NG, 64, 0, stream>>>(hbuf16, gptr, ss3, wb, bb, wm, bm, out);
}

// Round 14
// 223.947 us; speedup vs baseline: 1.2953x; 1.0360x over previous
//
#include <hip/hip_runtime.h>
#include <hip/hip_fp16.h>
#include <math.h>

// Problem constants (match reference)
#define NN 150000
#define NE 2400000
#define NG 1024
#define DIN 6
#define DH 32
#define DB 16
#define BN_EPS 1e-5f

#define FB 512                          // fused block size
#define NPBK 128                        // nodes per fused block
#define FUSED_BLOCKS ((NN + NPBK - 1) / NPBK)   // 1172
#define RED_BLKS 32                     // stage-1 reduction blocks

// bucket sort params
#define NB 512            // buckets
#define NPB 293           // nodes per bucket (512*293 = 150016 >= NN); NPB < 512 so 9 bits
#define SCH 4096          // edges per scatter block
#define EPB 16            // edges per thread in scatter
#define CAP 8192          // fixed region per bucket (expected ~4690 edges)
#define NSCAT ((NE + SCH - 1) / SCH)  // 586

// inclusive Hillis-Steele scan of 512 ints in LDS with 256 threads
#define SCAN512(scarr, t)                                     \
    for (int off = 1; off < 512; off <<= 1) {                 \
        int v0 = (t >= off) ? scarr[t - off] : 0;             \
        int v1 = scarr[t + 256 - off];                        \
        __syncthreads();                                      \
        if (t >= off) scarr[t] += v0;                         \
        scarr[t + 256] += v1;                                 \
        __syncthreads();                                      \
    }

__device__ inline void addh8(float* a, uint4 v) {
    const __half2* hp = (const __half2*)&v;
#pragma unroll
    for (int i = 0; i < 4; ++i) {
        float2 f = __half22float2(hp[i]);
        a[2 * i] += f.x; a[2 * i + 1] += f.y;
    }
}

// ===== init: bucket cursors + graph bounds + x->fp16 table =====
__global__ void init_cvt(const int* __restrict__ bat, const float* __restrict__ x,
                         int* __restrict__ bcur, int* __restrict__ gptr,
                         __half* __restrict__ x16) {
    int i = blockIdx.x * blockDim.x + threadIdx.x;
    if (i < NB) bcur[i] = i * CAP;
    if (i <= NG) {
        int lo = 0, hi = NN;
        while (lo < hi) {
            int mid = (lo + hi) >> 1;
            if (bat[mid] < i) lo = mid + 1; else hi = mid;
        }
        gptr[i] = lo;
    }
    if (i < NN) {
        const float2* xs = (const float2*)(x + (long)i * DIN);
        float2 p0 = xs[0], p1 = xs[1], p2 = xs[2];
        uint4 v;
        unsigned* vp = (unsigned*)&v;
        __half2 h0 = __floats2half2_rn(p0.x, p0.y);
        __half2 h1 = __floats2half2_rn(p1.x, p1.y);
        __half2 h2 = __floats2half2_rn(p2.x, p2.y);
        __half2 h3 = __floats2half2_rn(0.f, 0.f);
        vp[0] = *(unsigned*)&h0; vp[1] = *(unsigned*)&h1;
        vp[2] = *(unsigned*)&h2; vp[3] = *(unsigned*)&h3;
        ((uint4*)x16)[i] = v;
    }
}

// block-local binning -> packed (src<<9|dst_local) writes into fixed bucket regions
__global__ void bucket_scatter(const int* __restrict__ ei, int* __restrict__ bcur,
                               unsigned* __restrict__ ebuf) {
    __shared__ int hist[NB];
    __shared__ int sc[NB];
    __shared__ int lcur[NB];
    __shared__ int gbase[NB];
    __shared__ unsigned stage[SCH];
    __shared__ unsigned short stageb[SCH];
    int t = threadIdx.x;
    long e0 = (long)blockIdx.x * SCH;
    int s16[EPB], d16[EPB];
    for (int i = t; i < NB; i += 256) hist[i] = 0;
    __syncthreads();
#pragma unroll
    for (int k = 0; k < EPB; ++k) {
        long idx = e0 + k * 256 + t;
        if (idx < NE) {
            s16[k] = ei[idx];
            d16[k] = ei[NE + idx];
            atomicAdd(&hist[d16[k] / NPB], 1);
        } else d16[k] = -1;
    }
    __syncthreads();
    for (int i = t; i < NB; i += 256) sc[i] = hist[i];
    __syncthreads();
    SCAN512(sc, t);
    for (int i = t; i < NB; i += 256) lcur[i] = sc[i] - hist[i];
    __syncthreads();
#pragma unroll
    for (int k = 0; k < EPB; ++k) {
        if (d16[k] >= 0) {
            int b = d16[k] / NPB;
            int p = atomicAdd(&lcur[b], 1);
            stage[p] = ((unsigned)s16[k] << 9) | (unsigned)(d16[k] - b * NPB);
            stageb[p] = (unsigned short)b;
        }
    }
    __syncthreads();
    for (int i = t; i < NB; i += 256) {
        int h = hist[i];
        gbase[i] = h ? atomicAdd(&bcur[i], h) : 0;
    }
    __syncthreads();
    int cnt = (int)((NE - e0) < SCH ? (NE - e0) : SCH);
    for (int i = t; i < cnt; i += 256) {
        int b = stageb[i];
        ebuf[gbase[b] + (i - (sc[b] - hist[b]))] = stage[i];
    }
}

// per-bucket LDS counting sort -> csr_src (fixed stride) + rbeg/rend per node
__global__ void bucket_sort(const unsigned* __restrict__ ebuf, const int* __restrict__ bcur,
                            int* __restrict__ rbeg, int* __restrict__ rend,
                            int* __restrict__ csr_src) {
    __shared__ int deg[NB];
    __shared__ int sc[NB];
    __shared__ int cur[NB];
    __shared__ int srcbuf[CAP];
    int b = blockIdx.x, t = threadIdx.x;
    int node0 = b * NPB;
    int nlocal = (NN - node0) < NPB ? (NN - node0) : NPB;
    int ebase = b * CAP;
    int ecnt = bcur[b] - ebase;
    if (ecnt > CAP) ecnt = CAP;
    for (int i = t; i < NB; i += 256) deg[i] = 0;
    __syncthreads();
    for (int i = t; i < ecnt; i += 256) {
        atomicAdd(&deg[ebuf[ebase + i] & 511u], 1);
    }
    __syncthreads();
    for (int i = t; i < NB; i += 256) sc[i] = deg[i];
    __syncthreads();
    SCAN512(sc, t);
    for (int j = t; j < nlocal; j += 256) {
        int st = sc[j] - deg[j];
        rbeg[node0 + j] = ebase + st;
        rend[node0 + j] = ebase + st + deg[j];
        cur[j] = st;
    }
    __syncthreads();
    for (int i = t; i < ecnt; i += 256) {
        unsigned v = ebuf[ebase + i];
        int p = atomicAdd(&cur[v & 511u], 1);
        srcbuf[p] = (int)(v >> 9);
    }
    __syncthreads();
    for (int i = t; i < ecnt; i += 256) csr_src[ebase + i] = srcbuf[i];
}

// ======== fused layer 1: edge-split gather of x16 (L2-resident) + MLP + stats ========
// 128 nodes / block (512 thr), 4 threads / node (edge-split), quad-reduce agg.
__global__ void __launch_bounds__(FB) fused_gin6(
    const int* __restrict__ rbeg, const int* __restrict__ rend,
    const int* __restrict__ csr_src, const __half* __restrict__ x16,
    const float* __restrict__ w1, const float* __restrict__ b1,
    const float* __restrict__ w2, const float* __restrict__ b2,
    __half* __restrict__ out, float* __restrict__ partial) {
    __shared__ float sw1[DIN * DH];
    __shared__ float sw2[DH * DH];
    __shared__ float sb1[DH];
    __shared__ float sb2[DH];
    __shared__ float bsum[DH];
    __shared__ float bsq[DH];
    int t = threadIdx.x;
    for (int i = t; i < DIN * DH; i += FB) sw1[i] = w1[i];
    for (int i = t; i < DH * DH; i += FB) sw2[i] = w2[i];
    if (t < DH) { sb1[t] = b1[t]; sb2[t] = b2[t]; bsum[t] = 0.f; bsq[t] = 0.f; }
    __syncthreads();

    int nl = t >> 2, sub = t & 3;
    int node = blockIdx.x * NPBK + nl;
    bool valid = node < NN;
    int j0 = sub * 8;
    int qb = t & ~3;

    // ---- edge-split gather: thread sub takes edges beg+sub, beg+sub+4, ... ----
    const uint4* xb = (const uint4*)x16;
    float a[8] = {0.f, 0.f, 0.f, 0.f, 0.f, 0.f, 0.f, 0.f};
    int beg = 0, end = 0;
    if (valid) {
        beg = rbeg[node]; end = rend[node];
        if (sub == 0) addh8(a, xb[node]);    // self term once
    }
    for (int e = beg + sub; e < end; e += 4) addh8(a, xb[csr_src[e]]);
    // quad reduce -> every thread holds the full 6-ch (8 slot) agg
#pragma unroll
    for (int i = 0; i < 8; ++i) {
        a[i] += __shfl_xor(a[i], 1);
        a[i] += __shfl_xor(a[i], 2);
    }

    // ---- MLP layer A (IN=6, inputs local): thread computes its 8 outputs ----
    float u[8];
#pragma unroll
    for (int i = 0; i < 8; ++i) {
        int j = j0 + i;
        float acc = sb1[j];
#pragma unroll
        for (int k = 0; k < DIN; ++k) acc += a[k] * sw1[k * DH + j];
        u[i] = fmaxf(acc, 0.f);
    }

    // ---- MLP layer B via quad-shuffle exchange ----
    float r[8];
#pragma unroll
    for (int i = 0; i < 8; ++i) r[i] = sb2[j0 + i];
#pragma unroll
    for (int q = 0; q < 4; ++q) {
#pragma unroll
        for (int i = 0; i < 8; ++i) {
            float uk = __shfl(u[i], qb + q);
            int k = q * 8 + i;
            const float4* w4 = (const float4*)&sw2[k * DH + j0];
            float4 wa = w4[0], wb = w4[1];
            r[0] += uk * wa.x; r[1] += uk * wa.y; r[2] += uk * wa.z; r[3] += uk * wa.w;
            r[4] += uk * wb.x; r[5] += uk * wb.y; r[6] += uk * wb.z; r[7] += uk * wb.w;
        }
    }
#pragma unroll
    for (int i = 0; i < 8; ++i) r[i] = valid ? fmaxf(r[i], 0.f) : 0.f;

    if (valid) {
        uint4 o;
        unsigned* op = (unsigned*)&o;
#pragma unroll
        for (int i = 0; i < 4; ++i) {
            __half2 hh = __floats2half2_rn(r[2 * i], r[2 * i + 1]);
            op[i] = *(unsigned*)&hh;
        }
        ((uint4*)out)[(long)node * 4 + sub] = o;
    }

    // ---- stats ----
    float s[8], q[8];
#pragma unroll
    for (int i = 0; i < 8; ++i) { s[i] = r[i]; q[i] = r[i] * r[i]; }
#pragma unroll
    for (int o = 4; o < 64; o <<= 1) {
#pragma unroll
        for (int i = 0; i < 8; ++i) {
            s[i] += __shfl_xor(s[i], o);
            q[i] += __shfl_xor(q[i], o);
        }
    }
    if ((t & 63) < 4) {
#pragma unroll
        for (int i = 0; i < 8; ++i) {
            atomicAdd(&bsum[j0 + i], s[i]);
            atomicAdd(&bsq[j0 + i], q[i]);
        }
    }
    __syncthreads();
    if (t < 2 * DH) {
        float v = (t < DH) ? bsum[t] : bsq[t - DH];
        partial[(long)blockIdx.x * (2 * DH) + t] = v;
    }
}

// ======== fused layers 2/3 (fp16 h): BN fold from partial2 + gather + MLP ========
// 128 nodes / block (512 thr), 4 threads / node, 8-deep gather burst.
__global__ void __launch_bounds__(FB) fused_gin16(
    const int* __restrict__ rbeg, const int* __restrict__ rend,
    const int* __restrict__ csr_src,
    const __half* __restrict__ h, const float* __restrict__ partial2,
    const float* __restrict__ g, const float* __restrict__ be,
    const float* __restrict__ w1, const float* __restrict__ b1,
    const float* __restrict__ w2, const float* __restrict__ b2,
    __half* __restrict__ out, float* __restrict__ partial /* [gridDim][64] */) {
    __shared__ float sw1[DH * DH];
    __shared__ float sw2[DH * DH];
    __shared__ float sb1[DH];
    __shared__ float sb2[DH];
    __shared__ float bsum[DH];
    __shared__ float bsq[DH];
    __shared__ float sfold[8][64];
    __shared__ float sss[2 * DH];
    int t = threadIdx.x;
    for (int i = t; i < DH * DH; i += FB) { sw1[i] = w1[i]; sw2[i] = w2[i]; }
    if (t < DH) { sb1[t] = b1[t]; sb2[t] = b2[t]; bsum[t] = 0.f; bsq[t] = 0.f; }
    // ---- prologue: fold partial2 -> BN scale/shift (identical in every block) ----
    {
        int ch = t & 63, rg = t >> 6;          // 8 row groups
        float acc = 0.f;
        for (int r = rg; r < RED_BLKS; r += 8) acc += partial2[(long)r * 64 + ch];
        sfold[rg][ch] = acc;
    }
    __syncthreads();
    if (t < 64) {
        float s = 0.f;
#pragma unroll
        for (int k = 0; k < 8; ++k) s += sfold[k][t];
        sfold[0][t] = s;
    }
    __syncthreads();
    if (t < DH) {
        float mu = sfold[0][t] * (1.0f / NN);
        float var = sfold[0][DH + t] * (1.0f / NN) - mu * mu;
        float sc = g[t] * rsqrtf(var + BN_EPS);
        sss[t] = sc;
        sss[DH + t] = be[t] - mu * sc;
    }
    __syncthreads();

    int nl = t >> 2, sub = t & 3;
    int node = blockIdx.x * NPBK + nl;
    bool valid = node < NN;
    int j0 = sub * 8;
    int qb = t & ~3;      // quad base lane (same wave)

    // ---- gather (4 threads/node, 8 fp16 ch each = 16B loads), 8-deep burst ----
    const uint4* hb = (const uint4*)h;   // node row = 4 uint4
    float a[8] = {0.f, 0.f, 0.f, 0.f, 0.f, 0.f, 0.f, 0.f};
    int beg = 0, end = 0;
    if (valid) {
        beg = rbeg[node]; end = rend[node];
        addh8(a, hb[(long)node * 4 + sub]);     // self term
    }
    int e = beg;
    int nrem = end - beg;
    for (int i = 0; i < (nrem & ~7); i += 8) {
        int s0 = csr_src[e], s1 = csr_src[e + 1], s2 = csr_src[e + 2], s3 = csr_src[e + 3];
        int s4 = csr_src[e + 4], s5 = csr_src[e + 5], s6 = csr_src[e + 6], s7 = csr_src[e + 7];
        e += 8;
        uint4 v0 = hb[(long)s0 * 4 + sub];
        uint4 v1 = hb[(long)s1 * 4 + sub];
        uint4 v2 = hb[(long)s2 * 4 + sub];
        uint4 v3 = hb[(long)s3 * 4 + sub];
        uint4 v4 = hb[(long)s4 * 4 + sub];
        uint4 v5 = hb[(long)s5 * 4 + sub];
        uint4 v6 = hb[(long)s6 * 4 + sub];
        uint4 v7 = hb[(long)s7 * 4 + sub];
        addh8(a, v0); addh8(a, v1); addh8(a, v2); addh8(a, v3);
        addh8(a, v4); addh8(a, v5); addh8(a, v6); addh8(a, v7);
    }
    if (nrem & 4) {
        int s0 = csr_src[e], s1 = csr_src[e + 1], s2 = csr_src[e + 2], s3 = csr_src[e + 3];
        e += 4;
        uint4 v0 = hb[(long)s0 * 4 + sub];
        uint4 v1 = hb[(long)s1 * 4 + sub];
        uint4 v2 = hb[(long)s2 * 4 + sub];
        uint4 v3 = hb[(long)s3 * 4 + sub];
        addh8(a, v0); addh8(a, v1); addh8(a, v2); addh8(a, v3);
    }
    for (; e < end; ++e) addh8(a, hb[(long)csr_src[e] * 4 + sub]);

    // ---- BN affine fold (stays in registers) ----
    float cnt = (float)(end - beg + 1);
#pragma unroll
    for (int i = 0; i < 8; ++i)
        a[i] = a[i] * sss[j0 + i] + cnt * sss[DH + j0 + i];

    // ---- MLP layer A via quad-shuffle exchange ----
    float u[8];
#pragma unroll
    for (int i = 0; i < 8; ++i) u[i] = sb1[j0 + i];
#pragma unroll
    for (int q = 0; q < 4; ++q) {
#pragma unroll
        for (int i = 0; i < 8; ++i) {
            float ak = __shfl(a[i], qb + q);
            int k = q * 8 + i;
            const float4* w4 = (const float4*)&sw1[k * DH + j0];
            float4 wa = w4[0], wb = w4[1];
            u[0] += ak * wa.x; u[1] += ak * wa.y; u[2] += ak * wa.z; u[3] += ak * wa.w;
            u[4] += ak * wb.x; u[5] += ak * wb.y; u[6] += ak * wb.z; u[7] += ak * wb.w;
        }
    }
#pragma unroll
    for (int i = 0; i < 8; ++i) u[i] = fmaxf(u[i], 0.f);

    // ---- MLP layer B via quad-shuffle exchange ----
    float r[8];
#pragma unroll
    for (int i = 0; i < 8; ++i) r[i] = sb2[j0 + i];
#pragma unroll
    for (int q = 0; q < 4; ++q) {
#pragma unroll
        for (int i = 0; i < 8; ++i) {
            float uk = __shfl(u[i], qb + q);
            int k = q * 8 + i;
            const float4* w4 = (const float4*)&sw2[k * DH + j0];
            float4 wa = w4[0], wb = w4[1];
            r[0] += uk * wa.x; r[1] += uk * wa.y; r[2] += uk * wa.z; r[3] += uk * wa.w;
            r[4] += uk * wb.x; r[5] += uk * wb.y; r[6] += uk * wb.z; r[7] += uk * wb.w;
        }
    }
#pragma unroll
    for (int i = 0; i < 8; ++i) r[i] = valid ? fmaxf(r[i], 0.f) : 0.f;

    if (valid) {
        uint4 o;
        unsigned* op = (unsigned*)&o;
#pragma unroll
        for (int i = 0; i < 4; ++i) {
            __half2 hh = __floats2half2_rn(r[2 * i], r[2 * i + 1]);
            op[i] = *(unsigned*)&hh;
        }
        ((uint4*)out)[(long)node * 4 + sub] = o;
    }

    // ---- stats: butterfly over the 16 nodes in this wave, then LDS atomic ----
    float s[8], q[8];
#pragma unroll
    for (int i = 0; i < 8; ++i) { s[i] = r[i]; q[i] = r[i] * r[i]; }
#pragma unroll
    for (int o = 4; o < 64; o <<= 1) {
#pragma unroll
        for (int i = 0; i < 8; ++i) {
            s[i] += __shfl_xor(s[i], o);
            q[i] += __shfl_xor(q[i], o);
        }
    }
    if ((t & 63) < 4) {
#pragma unroll
        for (int i = 0; i < 8; ++i) {
            atomicAdd(&bsum[j0 + i], s[i]);
            atomicAdd(&bsq[j0 + i], q[i]);
        }
    }
    __syncthreads();
    if (t < 2 * DH) {
        float v = (t < DH) ? bsum[t] : bsq[t - DH];
        partial[(long)blockIdx.x * (2 * DH) + t] = v;
    }
}

// ===== stage 1: fold partial[nblk][64] -> partial2[RED_BLKS][64], coalesced =====
__global__ void reduce_partial(const float* __restrict__ partial, int nblk,
                               float* __restrict__ partial2) {
    __shared__ float sred[4][64];
    int t = threadIdx.x;           // 256
    int ch = t & 63, sub = t >> 6;
    int chunk = (nblk + RED_BLKS - 1) / RED_BLKS;
    int start = blockIdx.x * chunk;
    int end = start + chunk; if (end > nblk) end = nblk;
    float acc = 0.f;
    for (int r = start + sub; r < end; r += 4)
        acc += partial[(long)r * 64 + ch];
    sred[sub][ch] = acc;
    __syncthreads();
    if (t < 64)
        partial2[(long)blockIdx.x * 64 + t] =
            sred[0][t] + sred[1][t] + sred[2][t] + sred[3][t];
}

// ====== fused pool(BN fold from partial2) + head, one block per graph ======
__global__ void pool_head(const __half* __restrict__ h, const int* __restrict__ gptr,
                          const float* __restrict__ partial2,
                          const float* __restrict__ g, const float* __restrict__ be,
                          const float* __restrict__ wb, const float* __restrict__ bb,
                          const float* __restrict__ wm, const float* __restrict__ bm,
                          float* __restrict__ out) {
    __shared__ float swb[DH * DB];
    __shared__ float sbb[DB];
    __shared__ float swm[DB];
    __shared__ float semb[DH];
    __shared__ float sss[2 * DH];
    int g_ = blockIdx.x;
    int t = threadIdx.x;           // 64 threads
    for (int i = t; i < DH * DB; i += 64) swb[i] = wb[i];
    if (t < DB) { sbb[t] = bb[t]; swm[t] = wm[t]; }
    // prologue: fold partial2 -> BN scale/shift
    if (t < 64) {
        float acc = 0.f;
        for (int r = 0; r < RED_BLKS; ++r) acc += partial2[(long)r * 64 + t];
        sss[t] = acc;   // temp: raw sums
    }
    __syncthreads();
    if (t < DH) {
        float mu = sss[t] * (1.0f / NN);
        float var = sss[DH + t] * (1.0f / NN) - mu * mu;
        float sc = g[t] * rsqrtf(var + BN_EPS);
        float sh = be[t] - mu * sc;
        sss[t] = sc;
        sss[DH + t] = sh;
    }
    __syncthreads();
    int beg = gptr[g_], end = gptr[g_ + 1];
    int sub = t & 3, nt = t >> 2;  // 16 node slots x 4 quarters
    const uint4* hb = (const uint4*)h;
    float acc[8] = {0.f, 0.f, 0.f, 0.f, 0.f, 0.f, 0.f, 0.f};
    for (int n = beg + nt; n < end; n += 16) addh8(acc, hb[(long)n * 4 + sub]);
#pragma unroll
    for (int o = 4; o < 64; o <<= 1) {
#pragma unroll
        for (int i = 0; i < 8; ++i) acc[i] += __shfl_xor(acc[i], o);
    }
    if (t < 4) {
        int c = end - beg;
        int j0 = t * 8;
        float inv = (c > 0) ? 1.0f / (float)c : 0.f;
#pragma unroll
        for (int i = 0; i < 8; ++i)
            semb[j0 + i] = (c > 0) ? sss[j0 + i] * (acc[i] * inv) + sss[DH + j0 + i] : 0.f;
    }
    __syncthreads();
    float z = 0.f;
    if (t < DB) {
        z = sbb[t];
#pragma unroll
        for (int k = 0; k < DH; ++k) z += semb[k] * swb[k * DB + t];
        z = fmaxf(z, 0.f) * swm[t];
    }
#pragma unroll
    for (int o = 1; o < DB; o <<= 1) z += __shfl_xor(z, o);
    if (t == 0) out[g_] = 1.0f / (1.0f + expf(-(z + bm[0])));
}

extern "C" void kernel_launch(void* const* d_in, const int* in_sizes, int n_in,
                              void* d_out, int out_size, void* d_ws, size_t ws_size,
                              hipStream_t stream) {
    const float* x   = (const float*)d_in[0];
    const int*   ei  = (const int*)d_in[1];
    const int*   bat = (const int*)d_in[2];
    const float* w1a = (const float*)d_in[3];  const float* b1a = (const float*)d_in[4];
    const float* w1b = (const float*)d_in[5];  const float* b1b = (const float*)d_in[6];
    const float* g1  = (const float*)d_in[7];  const float* be1 = (const float*)d_in[8];
    const float* w2a = (const float*)d_in[9];  const float* b2a = (const float*)d_in[10];
    const float* w2b = (const float*)d_in[11]; const float* b2b = (const float*)d_in[12];
    const float* g2  = (const float*)d_in[13]; const float* be2 = (const float*)d_in[14];
    const float* w3a = (const float*)d_in[15]; const float* b3a = (const float*)d_in[16];
    const float* w3b = (const float*)d_in[17]; const float* b3b = (const float*)d_in[18];
    const float* g3  = (const float*)d_in[19]; const float* be3 = (const float*)d_in[20];
    const float* wb  = (const float*)d_in[21]; const float* bb  = (const float*)d_in[22];
    const float* wm  = (const float*)d_in[23]; const float* bm  = (const float*)d_in[24];
    float* out = (float*)d_out;

    // ---- workspace layout ----
    char* wsb = (char*)d_ws;
    __half* hbuf16 = (__half*)wsb;                              // NN*DH fp16 = 9.6 MB
    char* regB     = wsb + (size_t)NN * DH * 2;                 // NB*CAP*4 = 16.8 MB (ebuf, then abuf16)
    unsigned* ebuf = (unsigned*)regB;
    __half* abuf16 = (__half*)regB;
    int*   csr_src = (int*)(regB + (size_t)NB * CAP * 4);       // NB*CAP ints
    int*   rbeg    = csr_src + (long)NB * CAP;                  // NN
    int*   rend    = rbeg + NN;                                 // NN
    int*   bcur    = rend + NN;                                 // NB
    int*   gptr    = bcur + NB;                                 // NG+1
    float* partial2= (float*)(gptr + NG + 1);                   // RED_BLKS*64
    float* partial = partial2 + (long)RED_BLKS * 64;            // FUSED_BLOCKS*64
    __half* x16    = (__half*)(partial + (long)FUSED_BLOCKS * 2 * DH); // NN*8 fp16 = 2.4 MB

    const int B = 256;
    int blkN = (NN + B - 1) / B;

    // ---- init (bucket cursors + graph bounds + x16 table) ----
    init_cvt<<<blkN, B, 0, stream>>>(bat, x, bcur, gptr, x16);

    // ---- CSR: block-local binning then per-bucket LDS counting sort ----
    bucket_scatter<<<NSCAT, B, 0, stream>>>(ei, bcur, ebuf);
    bucket_sort<<<NB, B, 0, stream>>>(ebuf, bcur, rbeg, rend, csr_src);

    // ---- layer 1 (fused, L2-resident x16 gathers): -> hbuf16 ----
    fused_gin6<<<FUSED_BLOCKS, FB, 0, stream>>>(rbeg, rend, csr_src, x16,
                                                w1a, b1a, w1b, b1b, hbuf16, partial);
    reduce_partial<<<RED_BLKS, B, 0, stream>>>(partial, FUSED_BLOCKS, partial2);

    // ---- layer 2 (fused, BN1 fold in prologue): hbuf16 -> abuf16 ----
    fused_gin16<<<FUSED_BLOCKS, FB, 0, stream>>>(rbeg, rend, csr_src, hbuf16,
                                                 partial2, g1, be1,
                                                 w2a, b2a, w2b, b2b, abuf16, partial);
    reduce_partial<<<RED_BLKS, B, 0, stream>>>(partial, FUSED_BLOCKS, partial2);

    // ---- layer 3 (fused, BN2 fold in prologue): abuf16 -> hbuf16 ----
    fused_gin16<<<FUSED_BLOCKS, FB, 0, stream>>>(rbeg, rend, csr_src, abuf16,
                                                 partial2, g2, be2,
                                                 w3a, b3a, w3b, b3b, hbuf16, partial);
    reduce_partial<<<RED_BLKS, B, 0, stream>>>(partial, FUSED_BLOCKS, partial2);

    // ---- fused pool (BN3 fold in prologue) + head ----
    pool_head<<<NG, 64, 0, stream>>>(hbuf16, gptr, partial2, g3, be3,
                                     wb, bb, wm, bm, out);
}